// Round 12
// baseline (377.229 us; speedup 1.0000x reference)
//
#include <hip/hip_runtime.h>

#define NN 16
#define CC 64
#define TT 20
#define VV 150
#define HH 8
#define DD 32
#define OO 128
#define TV 3000
#define QCH 512
#define NPIX 48000
#define NEL 6144000  // N*O*T*V
#define YS 160       // padded v-stride of ycl (sv = v+2)

using bf16x8 = __attribute__((ext_vector_type(8))) short;
using f32x4  = __attribute__((ext_vector_type(4))) float;

#define GLD_LDS16(g, l) __builtin_amdgcn_global_load_lds( \
    (const __attribute__((address_space(1))) unsigned int*)(g), \
    (__attribute__((address_space(3))) unsigned int*)(l), 16, 0, 0)

__device__ __forceinline__ unsigned short f2bf(float f){
  union { float f; unsigned int i; } x; x.f = f;
  unsigned int r = x.i + 0x7fffu + ((x.i >> 16) & 1u);
  return (unsigned short)(r >> 16);
}
__device__ __forceinline__ float lrelu(float v){ return v > 0.f ? v : 0.1f*v; }

// ---------------- merged weight pre-swizzle ----------------
struct WprepJob { const float* W; unsigned short* dst; int MT, KT, rs, ks, koff, base; };
struct WprepArgs { WprepJob j[12]; };

__global__ __launch_bounds__(256) void k_wprep_all(WprepArgs a, int total){
  int g = blockIdx.x*256 + threadIdx.x;
  if (g >= total) return;
  int s = 0;
  #pragma unroll
  for (int q=1; q<12; q++) if (g >= a.j[q].base) s = q;
  const WprepJob jb = a.j[s];
  int gg = g - jb.base;
  int lane = gg & 63;
  int f = gg >> 6;
  int mt = f % jb.MT, kk = f / jb.MT;
  int row = mt*16 + (lane & 15);
  int kb = kk*32 + (lane >> 4)*8;
  unsigned int pk[4];
  #pragma unroll
  for (int j=0;j<4;j++){
    unsigned short x0 = f2bf(jb.W[(size_t)row*jb.rs + (size_t)(kb+2*j)*jb.ks + jb.koff]);
    unsigned short x1 = f2bf(jb.W[(size_t)row*jb.rs + (size_t)(kb+2*j+1)*jb.ks + jb.koff]);
    pk[j] = (unsigned int)x0 | ((unsigned int)x1 << 16);
  }
  unsigned int* dst = (unsigned int*)(jb.dst + (size_t)gg*8);
  #pragma unroll
  for (int j=0;j<4;j++) dst[j] = pk[j];
}

// ---------------- x prep ----------------
__global__ __launch_bounds__(256) void k_xprep(const float* __restrict__ x,
    const float* __restrict__ degree_emb, const int* __restrict__ all_degree,
    unsigned short* __restrict__ xbf,
    unsigned short* __restrict__ xcl, unsigned short* __restrict__ xclr){
  __shared__ float xl[64][153];
  int tid = threadIdx.x;
  int t = blockIdx.x, n = blockIdx.y;
  for (int idx=tid; idx<64*160; idx+=256){
    int c = idx/160, v = idx - c*160;
    float xv = 0.f;
    if (v < VV){
      xv = x[((size_t)(n*CC+c)*TT + t)*VV + v];
      xl[c][v] = xv;
    }
    xbf[((size_t)(n*CC+c)*TT + t)*160 + v] = f2bf(xv);
  }
  __syncthreads();
  size_t pixb = (size_t)(n*TT + t)*VV;
  for (int idx=tid; idx<4800; idx+=256){
    int v = idx >> 5, c2 = (idx & 31)*2;
    float a0 = xl[c2][v], a1 = xl[c2+1][v];
    unsigned int raw = (unsigned int)f2bf(a0) | ((unsigned int)f2bf(a1) << 16);
    float freq = __expf(-(float)(c2 >> 1) * 0.2878231366f);
    float arg = (float)v * freq;
    int dgi = all_degree[v % 25];
    float b0 = a0 + sinf(arg) + degree_emb[dgi*CC + c2];
    float b1 = a1 + cosf(arg) + degree_emb[dgi*CC + c2 + 1];
    unsigned int bi = (unsigned int)f2bf(b0) | ((unsigned int)f2bf(b1) << 16);
    *(unsigned int*)(xclr + (pixb + v)*CC + c2) = raw;
    *(unsigned int*)(xcl  + (pixb + v)*CC + c2) = bi;
  }
}

// ---------------- qkv MFMA ----------------
__global__ __launch_bounds__(256) void k_qkv_mfma(const unsigned short* __restrict__ xcl,
    const unsigned short* __restrict__ Wsw, const float* __restrict__ bq,
    unsigned short* __restrict__ qkv){
  int tid = threadIdx.x, wave = tid >> 6, lane = tid & 63;
  int l15 = lane & 15, lhi = lane >> 4;
  int pix0 = blockIdx.x*32;
  f32x4 acc[8][2];
  #pragma unroll
  for (int m=0;m<8;m++){ acc[m][0] = f32x4{0,0,0,0}; acc[m][1] = f32x4{0,0,0,0}; }
  #pragma unroll
  for (int kk=0;kk<2;kk++){
    bf16x8 bfr[2];
    #pragma unroll
    for (int q=0;q<2;q++)
      bfr[q] = *(const bf16x8*)(xcl + (size_t)(pix0 + q*16 + l15)*CC + kk*32 + lhi*8);
    #pragma unroll
    for (int m=0;m<8;m++){
      bf16x8 afr = *(const bf16x8*)(Wsw + ((size_t)(kk*32 + wave*8 + m)*64 + lane)*8);
      acc[m][0] = __builtin_amdgcn_mfma_f32_16x16x32_bf16(afr, bfr[0], acc[m][0], 0,0,0);
      acc[m][1] = __builtin_amdgcn_mfma_f32_16x16x32_bf16(afr, bfr[1], acc[m][1], 0,0,0);
    }
  }
  #pragma unroll
  for (int m=0;m<8;m++){
    int o0 = (wave*8 + m)*16 + lhi*4;
    float b0 = bq[o0], b1 = bq[o0+1], b2 = bq[o0+2], b3 = bq[o0+3];
    #pragma unroll
    for (int q=0;q<2;q++){
      int pix = pix0 + q*16 + l15;
      uint2 pk;
      pk.x = (unsigned int)f2bf(acc[m][q][0]+b0) | ((unsigned int)f2bf(acc[m][q][1]+b1) << 16);
      pk.y = (unsigned int)f2bf(acc[m][q][2]+b2) | ((unsigned int)f2bf(acc[m][q][3]+b3) << 16);
      *(uint2*)(qkv + (size_t)pix*QCH + o0) = pk;
    }
  }
}

// ---------------- att MFMA ----------------
__global__ __launch_bounds__(256) void k_att_mfma(const unsigned short* __restrict__ qkv,
    const float* __restrict__ alphas, const float* __restrict__ att0s,
    const float* __restrict__ sp_emb, const int* __restrict__ sp_pos,
    unsigned short* __restrict__ attT){
  int tid = threadIdx.x, wave = tid >> 6, lane = tid & 63;
  int l15 = lane & 15, lhi = lane >> 4;
  int vt = blockIdx.x, h = blockIdx.y, n = blockIdx.z;
  int uhalf = wave & 1, vsel = wave >> 1;
  int v = (vt*2 + vsel)*16 + l15;
  f32x4 acc[5];
  #pragma unroll
  for (int ui=0;ui<5;ui++) acc[ui] = f32x4{0,0,0,0};
  for (int t=0;t<TT;t++){
    size_t rowb = (size_t)(n*TT + t)*VV;
    bf16x8 bfr = bf16x8{};
    if (v < VV) bfr = *(const bf16x8*)(qkv + (rowb + v)*QCH + 256 + h*DD + lhi*8);
    #pragma unroll
    for (int ui=0;ui<5;ui++){
      int u = (uhalf*5+ui)*16 + l15;
      bf16x8 afr = bf16x8{};
      if (u < VV) afr = *(const bf16x8*)(qkv + (rowb + u)*QCH + h*DD + lhi*8);
      acc[ui] = __builtin_amdgcn_mfma_f32_16x16x32_bf16(afr, bfr, acc[ui], 0,0,0);
    }
  }
  float al = alphas[h];
  #pragma unroll
  for (int ui=0;ui<5;ui++){
    int u0 = (uhalf*5+ui)*16 + lhi*4;
    unsigned short hv[4];
    #pragma unroll
    for (int r=0;r<4;r++){
      int u = u0 + r;
      unsigned short val = 0;
      if (u < VV && v < VV){
        float gv = tanhf(acc[ui][r]*(1.f/640.f))*al
                 + att0s[((size_t)h*VV + u)*VV + v]
                 + sp_emb[sp_pos[u*VV + v]*HH + h];
        val = f2bf(gv);
      }
      hv[r] = val;
    }
    uint2 pk;
    pk.x = (unsigned int)hv[0] | ((unsigned int)hv[1] << 16);
    pk.y = (unsigned int)hv[2] | ((unsigned int)hv[3] << 16);
    *(uint2*)(attT + ((size_t)((n*HH+h)*160) + v)*160 + u0) = pk;
  }
}

// ---------------- yapply MFMA -> padded ycl (v-stride 160, sv=v+2) ----------------
__global__ __launch_bounds__(256) void k_yapply_mfma(const unsigned short* __restrict__ attT,
    const unsigned short* __restrict__ xbf, unsigned short* __restrict__ ycl){
  int tid = threadIdx.x, wave = tid >> 6, lane = tid & 63;
  int l15 = lane & 15, lhi = lane >> 4;
  int h = blockIdx.x, t = blockIdx.y, n = blockIdx.z;
  int vtb = (wave & 1)*5, ctb = (wave >> 1)*2;
  f32x4 acc[5][2];
  #pragma unroll
  for (int vi=0;vi<5;vi++){ acc[vi][0] = f32x4{0,0,0,0}; acc[vi][1] = f32x4{0,0,0,0}; }
  #pragma unroll
  for (int kk=0;kk<5;kk++){
    bf16x8 bfr[2];
    #pragma unroll
    for (int ci=0;ci<2;ci++){
      int c = (ctb+ci)*16 + l15;
      bfr[ci] = *(const bf16x8*)(xbf + ((size_t)(n*CC+c)*TT + t)*160 + kk*32 + lhi*8);
    }
    #pragma unroll
    for (int vi=0;vi<5;vi++){
      int v = (vtb+vi)*16 + l15;
      bf16x8 afr = *(const bf16x8*)(attT + ((size_t)((n*HH+h)*160) + v)*160 + kk*32 + lhi*8);
      #pragma unroll
      for (int ci=0;ci<2;ci++)
        acc[vi][ci] = __builtin_amdgcn_mfma_f32_16x16x32_bf16(afr, bfr[ci], acc[vi][ci], 0,0,0);
    }
  }
  size_t pixb = (size_t)(n*TT + t)*YS;
  if (tid < 128){
    int sv = tid >> 6, cc = tid & 63;
    ycl[(pixb + sv)*QCH + h*CC + cc] = 0;
  }
  #pragma unroll
  for (int vi=0;vi<5;vi++){
    int v0 = (vtb+vi)*16 + lhi*4;
    #pragma unroll
    for (int ci=0;ci<2;ci++){
      int c = (ctb+ci)*16 + l15;
      #pragma unroll
      for (int r=0;r<4;r++){
        int v = v0 + r;
        if (v < VV)
          ycl[(pixb + v + 2)*QCH + h*CC + c] = f2bf(acc[vi][ci][r]);
        else if (v < 158)
          ycl[(pixb + v + 2)*QCH + h*CC + c] = 0;
      }
    }
  }
}

// ---------------- conv_out MFMA: grid (5,10,16) x 512thr; wave = 4m x 1v x 1t ----------------
__global__ __launch_bounds__(512) void k_conv_out_mfma(const unsigned short* __restrict__ ycl,
    const unsigned short* __restrict__ Wsw, float* __restrict__ out, float* __restrict__ psum){
  __shared__ unsigned short As[20480];   // 40 KB
  __shared__ float ws_ps[8][64][2];      // 4 KB
  int tid = threadIdx.x, wave = tid >> 6, lane = tid & 63;
  int l15 = lane & 15, lhi = lane >> 4;
  int vt = blockIdx.x, tp = blockIdx.y, n = blockIdx.z;
  int mtb = (wave & 1)*4;
  int vsel = (wave >> 1) & 1;
  int tsel = wave >> 2;
  int t0 = tp*2 + tsel;
  int v = vt*32 + vsel*16 + l15;
  int vload = v < 151 ? v : 151;
  f32x4 acc[4];
  #pragma unroll
  for (int m=0;m<4;m++) acc[m] = f32x4{0,0,0,0};
  const unsigned short* yb = ycl + ((size_t)(n*TT + t0)*YS + vload)*QCH + lhi*8;

  #define STAGE_OUT(kk_) { \
    _Pragma("unroll") \
    for (int it=0; it<5; it++){ \
      int f = it*8 + wave; \
      const unsigned short* gsrc = Wsw + (size_t)(f>>3)*65536 + (size_t)((kk_)*8 + (f&7))*512 + lane*8; \
      GLD_LDS16(gsrc, &As[f*512 + lane*8]); \
    } }

  for (int kk=0; kk<16; kk++){
    __syncthreads();
    STAGE_OUT(kk);
    bf16x8 bfr[5];
    #pragma unroll
    for (int kv=0;kv<5;kv++)
      bfr[kv] = *(const bf16x8*)(yb + (size_t)kv*QCH + kk*32);
    asm volatile("s_waitcnt vmcnt(0)" ::: "memory");
    __syncthreads();
    #pragma unroll
    for (int kv=0; kv<5; kv++){
      #pragma unroll
      for (int m=0;m<4;m++){
        bf16x8 afr = *(const bf16x8*)(&As[(kv*8 + mtb + m)*512 + lane*8]);
        acc[m] = __builtin_amdgcn_mfma_f32_16x16x32_bf16(afr, bfr[kv], acc[m], 0,0,0);
      }
    }
  }
  bool vok = v < VV;
  if (vok){
    size_t pb = ((size_t)(n*TT + t0)*VV + v)*OO;
    #pragma unroll
    for (int m=0;m<4;m++){
      int o0 = (mtb+m)*16 + lhi*4;
      *(float4*)(out + pb + o0) = make_float4(acc[m][0], acc[m][1], acc[m][2], acc[m][3]);
    }
  }
  #pragma unroll
  for (int m=0;m<4;m++){
    #pragma unroll
    for (int r=0;r<4;r++){
      float a0 = vok ? acc[m][r] : 0.f;
      float s = a0;
      float q = a0*a0;
      #pragma unroll
      for (int off=1; off<16; off<<=1){ s += __shfl_xor(s, off); q += __shfl_xor(q, off); }
      if (l15 == 0){
        ws_ps[wave][m*16 + lhi*4 + r][0] = s;
        ws_ps[wave][m*16 + lhi*4 + r][1] = q;
      }
    }
  }
  __syncthreads();
  if (tid < 128){
    int half = tid >> 6, cw = tid & 63;
    float s = ws_ps[half][cw][0] + ws_ps[half+2][cw][0] + ws_ps[half+4][cw][0] + ws_ps[half+6][cw][0];
    float q = ws_ps[half][cw][1] + ws_ps[half+2][cw][1] + ws_ps[half+4][cw][1] + ws_ps[half+6][cw][1];
    int part = blockIdx.x + 5*blockIdx.y + 50*blockIdx.z;
    psum[(size_t)part*256 + tid] = s;
    psum[(size_t)part*256 + 128 + tid] = q;
  }
}

// ---------------- 1x1 conv MFMA + fused stats (tpad for T-padded input) ----------------
__global__ __launch_bounds__(256) void k_conv1x1_mfma(const unsigned short* __restrict__ in,
    const unsigned short* __restrict__ Wsw, float* __restrict__ out, int KT, int tpad,
    float* __restrict__ psum){
  __shared__ float ws_ps[4][64][2];
  int tid = threadIdx.x, wave = tid >> 6, lane = tid & 63;
  int l15 = lane & 15, lhi = lane >> 4;
  int mtb = (wave & 1)*4;
  int pg = wave >> 1;
  int pixb = blockIdx.x*64 + pg*32;
  int KD = KT*32;
  int ipix[2];
  #pragma unroll
  for (int pj=0;pj<2;pj++){
    int pix = pixb + pj*16 + l15;
    ipix[pj] = tpad ? pix + (2*(pix/3000)+1)*150 : pix;
  }
  f32x4 acc[4][2];
  #pragma unroll
  for (int m=0;m<4;m++){ acc[m][0] = f32x4{0,0,0,0}; acc[m][1] = f32x4{0,0,0,0}; }
  for (int kk=0; kk<KT; kk++){
    bf16x8 bfr[2];
    #pragma unroll
    for (int pj=0;pj<2;pj++)
      bfr[pj] = *(const bf16x8*)(in + (size_t)ipix[pj]*KD + kk*32 + lhi*8);
    #pragma unroll
    for (int m=0;m<4;m++){
      bf16x8 afr = *(const bf16x8*)(Wsw + ((size_t)(kk*8 + mtb + m)*64 + lane)*8);
      acc[m][0] = __builtin_amdgcn_mfma_f32_16x16x32_bf16(afr, bfr[0], acc[m][0], 0,0,0);
      acc[m][1] = __builtin_amdgcn_mfma_f32_16x16x32_bf16(afr, bfr[1], acc[m][1], 0,0,0);
    }
  }
  #pragma unroll
  for (int m=0;m<4;m++){
    int o0 = (mtb+m)*16 + lhi*4;
    #pragma unroll
    for (int pj=0;pj<2;pj++){
      int pix = pixb + pj*16 + l15;
      *(float4*)(out + (size_t)pix*OO + o0) = make_float4(acc[m][pj][0], acc[m][pj][1], acc[m][pj][2], acc[m][pj][3]);
    }
  }
  #pragma unroll
  for (int m=0;m<4;m++){
    #pragma unroll
    for (int r=0;r<4;r++){
      float a0 = acc[m][0][r], a1 = acc[m][1][r];
      float s = a0 + a1;
      float q = a0*a0 + a1*a1;
      #pragma unroll
      for (int off=1; off<16; off<<=1){ s += __shfl_xor(s, off); q += __shfl_xor(q, off); }
      if (l15 == 0){
        ws_ps[wave][m*16 + lhi*4 + r][0] = s;
        ws_ps[wave][m*16 + lhi*4 + r][1] = q;
      }
    }
  }
  __syncthreads();
  if (tid < 128){
    int half = tid >> 6, cw = tid & 63;
    float s = ws_ps[half][cw][0] + ws_ps[half+2][cw][0];
    float q = ws_ps[half][cw][1] + ws_ps[half+2][cw][1];
    psum[(size_t)blockIdx.x*256 + tid] = s;
    psum[(size_t)blockIdx.x*256 + 128 + tid] = q;
  }
}

// ---------------- conv_t MFMA: grid (5,10,16) x 512thr; wave = 4m x 1v x 1t ----------------
__global__ __launch_bounds__(512) void k_conv_t_mfma(const unsigned short* __restrict__ in,
    const unsigned short* __restrict__ Wsw, float* __restrict__ out, float* __restrict__ psum){
  __shared__ unsigned short As[12288];   // 24 KB
  __shared__ float ws_ps[8][64][2];
  int tid = threadIdx.x, wave = tid >> 6, lane = tid & 63;
  int l15 = lane & 15, lhi = lane >> 4;
  int vt = blockIdx.x, tp = blockIdx.y, n = blockIdx.z;
  int mtb = (wave & 1)*4;
  int vsel = (wave >> 1) & 1;
  int tsel = wave >> 2;
  int t0 = tp*2 + tsel;
  int v = vt*32 + vsel*16 + l15;
  int vload = v < 149 ? v : 149;
  bool vok = v < VV;
  const unsigned short* ib = in + ((size_t)(n*22 + t0)*VV + vload)*OO + lhi*8;
  f32x4 acc[4];
  #pragma unroll
  for (int m=0;m<4;m++) acc[m] = f32x4{0,0,0,0};

  #define STAGE_T(kk_) { \
    _Pragma("unroll") \
    for (int it=0; it<3; it++){ \
      int f = it*8 + wave; \
      const unsigned short* gsrc = Wsw + (size_t)(f>>3)*16384 + (size_t)((kk_)*8 + (f&7))*512 + lane*8; \
      GLD_LDS16(gsrc, &As[f*512 + lane*8]); \
    } }

  for (int kk=0; kk<4; kk++){
    __syncthreads();
    STAGE_T(kk);
    bf16x8 bfr[3];
    #pragma unroll
    for (int r=0;r<3;r++)
      bfr[r] = *(const bf16x8*)(ib + (size_t)r*VV*OO + kk*32);
    asm volatile("s_waitcnt vmcnt(0)" ::: "memory");
    __syncthreads();
    #pragma unroll
    for (int kt=0; kt<3; kt++){
      #pragma unroll
      for (int m=0;m<4;m++){
        bf16x8 afr = *(const bf16x8*)(&As[(kt*8 + mtb + m)*512 + lane*8]);
        acc[m] = __builtin_amdgcn_mfma_f32_16x16x32_bf16(afr, bfr[kt], acc[m], 0,0,0);
      }
    }
  }
  if (vok){
    size_t pb = ((size_t)(n*TT + t0)*VV + v)*OO;
    #pragma unroll
    for (int m=0;m<4;m++){
      int o0 = (mtb+m)*16 + lhi*4;
      *(float4*)(out + pb + o0) = make_float4(acc[m][0], acc[m][1], acc[m][2], acc[m][3]);
    }
  }
  #pragma unroll
  for (int m=0;m<4;m++){
    #pragma unroll
    for (int r=0;r<4;r++){
      float a0 = vok ? acc[m][r] : 0.f;
      float s = a0;
      float q = a0*a0;
      #pragma unroll
      for (int off=1; off<16; off<<=1){ s += __shfl_xor(s, off); q += __shfl_xor(q, off); }
      if (l15 == 0){
        ws_ps[wave][m*16 + lhi*4 + r][0] = s;
        ws_ps[wave][m*16 + lhi*4 + r][1] = q;
      }
    }
  }
  __syncthreads();
  if (tid < 128){
    int half = tid >> 6, cw = tid & 63;
    float s = ws_ps[half][cw][0] + ws_ps[half+2][cw][0] + ws_ps[half+4][cw][0] + ws_ps[half+6][cw][0];
    float q = ws_ps[half][cw][1] + ws_ps[half+2][cw][1] + ws_ps[half+4][cw][1] + ws_ps[half+6][cw][1];
    int part = blockIdx.x + 5*blockIdx.y + 50*blockIdx.z;
    psum[(size_t)part*256 + tid] = s;
    psum[(size_t)part*256 + 128 + tid] = q;
  }
}

// ---------------- generic stats stage 2 (dual) ----------------
__global__ __launch_bounds__(64) void k_stats2g(const float* __restrict__ psA, int nA, float* __restrict__ stA,
    const float* __restrict__ psB, int nB, float* __restrict__ stB){
  int ch = blockIdx.x & 127, tid = threadIdx.x;
  const float* ps; float* st; int nb;
  if (blockIdx.x < 128){ ps = psA; st = stA; nb = nA; }
  else { ps = psB; st = stB; nb = nB; }
  float s = 0.f, q = 0.f;
  for (int i=tid; i<nb; i+=64){
    s += ps[(size_t)i*256 + ch];
    q += ps[(size_t)i*256 + 128 + ch];
  }
  #pragma unroll
  for (int off=32; off; off>>=1){ s += __shfl_down(s, off); q += __shfl_down(q, off); }
  if (tid == 0){
    float m = s * (1.f/48000.f);
    float var = q * (1.f/48000.f) - m*m;
    st[ch*2] = m;
    st[ch*2+1] = rsqrtf(var + 1e-5f);
  }
}

// ---------------- xs1 = bf16(lrelu(bn(c) + bn_rs(res))), unpadded ----------------
__global__ __launch_bounds__(256) void k_bn_xs(const float* __restrict__ c,
    const float* __restrict__ st, const float* __restrict__ g, const float* __restrict__ be,
    const float* __restrict__ res, const float* __restrict__ st0,
    const float* __restrict__ g0, const float* __restrict__ be0,
    unsigned short* __restrict__ xs){
  int i = (blockIdx.x*256 + threadIdx.x)*4;
  if (i >= NEL) return;
  int ch = i & 127;
  float4 v = *(const float4*)(c + i);
  float4 r = *(const float4*)(res + i);
  float rs0 = (r.x - st0[ch*2+0]) * st0[ch*2+1] * g0[ch+0] + be0[ch+0];
  float rs1 = (r.y - st0[ch*2+2]) * st0[ch*2+3] * g0[ch+1] + be0[ch+1];
  float rs2 = (r.z - st0[ch*2+4]) * st0[ch*2+5] * g0[ch+2] + be0[ch+2];
  float rs3 = (r.w - st0[ch*2+6]) * st0[ch*2+7] * g0[ch+3] + be0[ch+3];
  float o0 = lrelu((v.x - st[ch*2+0]) * st[ch*2+1] * g[ch+0] + be[ch+0] + rs0);
  float o1 = lrelu((v.y - st[ch*2+2]) * st[ch*2+3] * g[ch+1] + be[ch+1] + rs1);
  float o2 = lrelu((v.z - st[ch*2+4]) * st[ch*2+5] * g[ch+2] + be[ch+2] + rs2);
  float o3 = lrelu((v.w - st[ch*2+6]) * st[ch*2+7] * g[ch+3] + be[ch+3] + rs3);
  uint2 pk;
  pk.x = (unsigned int)f2bf(o0) | ((unsigned int)f2bf(o1) << 16);
  pk.y = (unsigned int)f2bf(o2) | ((unsigned int)f2bf(o3) << 16);
  *(uint2*)(xs + i) = pk;
}

// ---------------- xs2 (T-padded [n][22][150][128]); pad slices zeroed ----------------
#define NQ4 1536000   // NEL/4
__global__ __launch_bounds__(256) void k_bn_xs_pad(const float* __restrict__ c,
    const float* __restrict__ st, const float* __restrict__ g, const float* __restrict__ be,
    const float* __restrict__ res, const float* __restrict__ st0,
    const float* __restrict__ g0, const float* __restrict__ be0,
    unsigned short* __restrict__ xs){
  int gi = blockIdx.x*256 + threadIdx.x;
  if (gi >= NQ4){
    int j = gi - NQ4;
    if (j >= 153600) return;
    int p = j*4;
    int n = p / 38400;
    int rem = p - n*38400;
    int side = rem / 19200;
    int off = rem - side*19200;
    int tq = side ? 21 : 0;
    uint2 z = {0,0};
    *(uint2*)(xs + (size_t)(n*22 + tq)*19200 + off) = z;
    return;
  }
  int i = gi*4;
  int ch = i & 127;
  int n = i / 384000;
  float4 v = *(const float4*)(c + i);
  float4 r = *(const float4*)(res + i);
  float rs0 = (r.x - st0[ch*2+0]) * st0[ch*2+1] * g0[ch+0] + be0[ch+0];
  float rs1 = (r.y - st0[ch*2+2]) * st0[ch*2+3] * g0[ch+1] + be0[ch+1];
  float rs2 = (r.z - st0[ch*2+4]) * st0[ch*2+5] * g0[ch+2] + be0[ch+2];
  float rs3 = (r.w - st0[ch*2+6]) * st0[ch*2+7] * g0[ch+3] + be0[ch+3];
  float o0 = lrelu((v.x - st[ch*2+0]) * st[ch*2+1] * g[ch+0] + be[ch+0] + rs0);
  float o1 = lrelu((v.y - st[ch*2+2]) * st[ch*2+3] * g[ch+1] + be[ch+1] + rs1);
  float o2 = lrelu((v.z - st[ch*2+4]) * st[ch*2+5] * g[ch+2] + be[ch+2] + rs2);
  float o3 = lrelu((v.w - st[ch*2+6]) * st[ch*2+7] * g[ch+3] + be[ch+3] + rs3);
  uint2 pk;
  pk.x = (unsigned int)f2bf(o0) | ((unsigned int)f2bf(o1) << 16);
  pk.y = (unsigned int)f2bf(o2) | ((unsigned int)f2bf(o3) << 16);
  *(uint2*)(xs + (size_t)i + (size_t)(2*n+1)*19200) = pk;
}

// ---------------- final: grid (20,16,2) ----------------
__global__ __launch_bounds__(256) void k_final_cl(const float* __restrict__ c3,
    const float* __restrict__ st3, const float* __restrict__ g3, const float* __restrict__ be3,
    const float* __restrict__ c4, const float* __restrict__ st4, const float* __restrict__ g4,
    const float* __restrict__ be4, float* __restrict__ out){
  __shared__ float tile[64][153];
  int tid = threadIdx.x;
  int t = blockIdx.x, n = blockIdx.y;
  int ch0 = blockIdx.z*64;
  size_t pixb = (size_t)(n*TT + t)*VV;
  for (int idx=tid; idx<VV*64; idx+=256){
    int v = idx >> 6, cc = idx & 63;
    int ch = ch0 + cc;
    float a = (c3[(pixb+v)*OO + ch] - st3[ch*2]) * st3[ch*2+1] * g3[ch] + be3[ch];
    float b = (c4[(pixb+v)*OO + ch] - st4[ch*2]) * st4[ch*2+1] * g4[ch] + be4[ch];
    tile[cc][v] = lrelu(a + b);
  }
  __syncthreads();
  for (int idx=tid; idx<64*VV; idx+=256){
    int cc = idx / VV, v = idx - cc*VV;
    out[((size_t)(n*OO + ch0 + cc)*TT + t)*VV + v] = tile[cc][v];
  }
}

extern "C" void kernel_launch(void* const* d_in, const int* in_sizes, int n_in,
                              void* d_out, int out_size, void* d_ws, size_t ws_size,
                              hipStream_t stream) {
  const float* x        = (const float*)d_in[0];
  const float* W_qkv    = (const float*)d_in[1];
  const float* b_qkv    = (const float*)d_in[2];
  const float* alphas   = (const float*)d_in[3];
  const float* att0s    = (const float*)d_in[4];
  const float* degree_emb = (const float*)d_in[5];
  const float* spatial_emb = (const float*)d_in[6];
  const float* W_out    = (const float*)d_in[7];
  const float* g_out    = (const float*)d_in[9];
  const float* be_out   = (const float*)d_in[10];
  const float* W_ff     = (const float*)d_in[11];
  const float* g_ff     = (const float*)d_in[13];
  const float* be_ff    = (const float*)d_in[14];
  const float* W_t      = (const float*)d_in[15];
  const float* g_t      = (const float*)d_in[17];
  const float* be_t     = (const float*)d_in[18];
  const float* W_rs     = (const float*)d_in[19];
  const float* g_rs     = (const float*)d_in[21];
  const float* be_rs    = (const float*)d_in[22];
  const float* W_rt     = (const float*)d_in[23];
  const float* g_rt     = (const float*)d_in[25];
  const float* be_rt    = (const float*)d_in[26];
  const int* all_degree = (const int*)d_in[27];
  const int* spatial_pos= (const int*)d_in[28];

  char* ws = (char*)d_ws;
  unsigned short* qkvcl = (unsigned short*)(ws + 0);
  unsigned short* ycl   = qkvcl;
  float* c4  = (float*)(ws + 0);
  unsigned short* xcl = (unsigned short*)(ws + 52500000);
  float* c1 = (float*)(ws + 52500000);
  float* c2 = c1, *c3 = c1;
  unsigned short* attT = (unsigned short*)(ws + 77100000);
  float* rsb = (float*)(ws + 77100000);
  unsigned short* xclr = (unsigned short*)(ws + 101700000);
  unsigned short* xs1  = (unsigned short*)(ws + 101700000);
  unsigned short* xbf  = (unsigned short*)(ws + 114000000);
  unsigned short* xs2  = (unsigned short*)(ws + 114000000);
  unsigned short* Wq_sw  = (unsigned short*)(ws + 127600000);
  unsigned short* Wout_sw= (unsigned short*)(ws + 127600000 + 65536);
  unsigned short* Wff_sw = (unsigned short*)(ws + 127600000 + 720896);
  unsigned short* Wrt_sw = (unsigned short*)(ws + 127600000 + 753664);
  unsigned short* Wt_sw  = (unsigned short*)(ws + 127600000 + 786432);
  unsigned short* Wrs_sw = (unsigned short*)(ws + 127600000 + 884736);
  float* stats = (float*)(ws + 128600000);
  float* psumA = (float*)(ws + 128700000);          // 800 x 256 f = 819200 B
  float* psumB = (float*)(ws + 129600000);          // 800 x 256 f
  float* out = (float*)d_out;

  WprepArgs wa;
  int base = 0, sz;
  sz = 32*2*64; wa.j[0] = {W_qkv, Wq_sw, 32, 2, 64, 1, 0, base}; base += sz;
  for (int kv=0; kv<5; kv++){
    sz = 8*16*64; wa.j[1+kv] = {W_out, Wout_sw + kv*65536, 8, 16, 2560, 5, kv, base}; base += sz;
  }
  sz = 8*4*64; wa.j[6] = {W_ff, Wff_sw, 8, 4, 128, 1, 0, base}; base += sz;
  sz = 8*4*64; wa.j[7] = {W_rt, Wrt_sw, 8, 4, 128, 1, 0, base}; base += sz;
  for (int kt=0; kt<3; kt++){
    sz = 8*4*64; wa.j[8+kt] = {W_t, Wt_sw + kt*16384, 8, 4, 384, 3, kt, base}; base += sz;
  }
  sz = 8*2*64; wa.j[11] = {W_rs, Wrs_sw, 8, 2, 64, 1, 0, base}; base += sz;
  int total = base;

  k_wprep_all<<<(total+255)/256, 256, 0, stream>>>(wa, total);
  k_xprep<<<dim3(20,16), 256, 0, stream>>>(x, degree_emb, all_degree, xbf, xcl, xclr);
  k_qkv_mfma<<<1500, 256, 0, stream>>>(xcl, Wq_sw, b_qkv, qkvcl);
  k_att_mfma<<<dim3(5,8,16), 256, 0, stream>>>(qkvcl, alphas, att0s, spatial_emb, spatial_pos, attT);
  k_yapply_mfma<<<dim3(8,20,16), 256, 0, stream>>>(attT, xbf, ycl);

  k_conv1x1_mfma<<<750, 256, 0, stream>>>(xclr, Wrs_sw, rsb, 2, 0, psumA);
  k_conv_out_mfma<<<dim3(5,10,16), 512, 0, stream>>>(ycl, Wout_sw, c1, psumB);
  k_stats2g<<<256, 64, 0, stream>>>(psumA, 750, stats + 0, psumB, 800, stats + 256);
  k_bn_xs<<<6000, 256, 0, stream>>>(c1, stats + 256, g_out, be_out,
                                    rsb, stats + 0, g_rs, be_rs, xs1);

  k_conv1x1_mfma<<<750, 256, 0, stream>>>(xs1, Wff_sw, c2, 4, 0, psumA);
  k_stats2g<<<128, 64, 0, stream>>>(psumA, 750, stats + 512, psumA, 0, stats + 512);
  k_bn_xs_pad<<<6600, 256, 0, stream>>>(c2, stats + 512, g_ff, be_ff,
                                        rsb, stats + 0, g_rs, be_rs, xs2);

  k_conv_t_mfma<<<dim3(5,10,16), 512, 0, stream>>>(xs2, Wt_sw, c3, psumA);
  k_conv1x1_mfma<<<750, 256, 0, stream>>>(xs2, Wrt_sw, c4, 4, 1, psumB);
  k_stats2g<<<256, 64, 0, stream>>>(psumA, 800, stats + 768, psumB, 750, stats + 1024);
  k_final_cl<<<dim3(20,16,2), 256, 0, stream>>>(c3, stats + 768, g_t, be_t,
                                                c4, stats + 1024, g_rt, be_rt, out);
}

// Round 13
// 358.812 us; speedup vs baseline: 1.0513x; 1.0513x over previous
//
#include <hip/hip_runtime.h>

#define NN 16
#define CC 64
#define TT 20
#define VV 150
#define HH 8
#define DD 32
#define OO 128
#define TV 3000
#define QCH 512
#define NPIX 48000
#define NEL 6144000  // N*O*T*V
#define YS 160       // padded v-stride of ycl (sv = v+2)

using bf16x8 = __attribute__((ext_vector_type(8))) short;
using f32x4  = __attribute__((ext_vector_type(4))) float;

#define GLD_LDS16(g, l) __builtin_amdgcn_global_load_lds( \
    (const __attribute__((address_space(1))) unsigned int*)(g), \
    (__attribute__((address_space(3))) unsigned int*)(l), 16, 0, 0)

__device__ __forceinline__ unsigned short f2bf(float f){
  union { float f; unsigned int i; } x; x.f = f;
  unsigned int r = x.i + 0x7fffu + ((x.i >> 16) & 1u);
  return (unsigned short)(r >> 16);
}
__device__ __forceinline__ float lrelu(float v){ return v > 0.f ? v : 0.1f*v; }

// ---------------- merged weight pre-swizzle ----------------
struct WprepJob { const float* W; unsigned short* dst; int MT, KT, rs, ks, koff, base; };
struct WprepArgs { WprepJob j[12]; };

__global__ __launch_bounds__(256) void k_wprep_all(WprepArgs a, int total){
  int g = blockIdx.x*256 + threadIdx.x;
  if (g >= total) return;
  int s = 0;
  #pragma unroll
  for (int q=1; q<12; q++) if (g >= a.j[q].base) s = q;
  const WprepJob jb = a.j[s];
  int gg = g - jb.base;
  int lane = gg & 63;
  int f = gg >> 6;
  int mt = f % jb.MT, kk = f / jb.MT;
  int row = mt*16 + (lane & 15);
  int kb = kk*32 + (lane >> 4)*8;
  unsigned int pk[4];
  #pragma unroll
  for (int j=0;j<4;j++){
    unsigned short x0 = f2bf(jb.W[(size_t)row*jb.rs + (size_t)(kb+2*j)*jb.ks + jb.koff]);
    unsigned short x1 = f2bf(jb.W[(size_t)row*jb.rs + (size_t)(kb+2*j+1)*jb.ks + jb.koff]);
    pk[j] = (unsigned int)x0 | ((unsigned int)x1 << 16);
  }
  unsigned int* dst = (unsigned int*)(jb.dst + (size_t)gg*8);
  #pragma unroll
  for (int j=0;j<4;j++) dst[j] = pk[j];
}

// ---------------- x prep ----------------
__global__ __launch_bounds__(256) void k_xprep(const float* __restrict__ x,
    const float* __restrict__ degree_emb, const int* __restrict__ all_degree,
    unsigned short* __restrict__ xbf,
    unsigned short* __restrict__ xcl, unsigned short* __restrict__ xclr){
  __shared__ float xl[64][153];
  int tid = threadIdx.x;
  int t = blockIdx.x, n = blockIdx.y;
  for (int idx=tid; idx<64*160; idx+=256){
    int c = idx/160, v = idx - c*160;
    float xv = 0.f;
    if (v < VV){
      xv = x[((size_t)(n*CC+c)*TT + t)*VV + v];
      xl[c][v] = xv;
    }
    xbf[((size_t)(n*CC+c)*TT + t)*160 + v] = f2bf(xv);
  }
  __syncthreads();
  size_t pixb = (size_t)(n*TT + t)*VV;
  for (int idx=tid; idx<4800; idx+=256){
    int v = idx >> 5, c2 = (idx & 31)*2;
    float a0 = xl[c2][v], a1 = xl[c2+1][v];
    unsigned int raw = (unsigned int)f2bf(a0) | ((unsigned int)f2bf(a1) << 16);
    float freq = __expf(-(float)(c2 >> 1) * 0.2878231366f);
    float arg = (float)v * freq;
    int dgi = all_degree[v % 25];
    float b0 = a0 + sinf(arg) + degree_emb[dgi*CC + c2];
    float b1 = a1 + cosf(arg) + degree_emb[dgi*CC + c2 + 1];
    unsigned int bi = (unsigned int)f2bf(b0) | ((unsigned int)f2bf(b1) << 16);
    *(unsigned int*)(xclr + (pixb + v)*CC + c2) = raw;
    *(unsigned int*)(xcl  + (pixb + v)*CC + c2) = bi;
  }
}

// ---------------- qkv MFMA ----------------
__global__ __launch_bounds__(256) void k_qkv_mfma(const unsigned short* __restrict__ xcl,
    const unsigned short* __restrict__ Wsw, const float* __restrict__ bq,
    unsigned short* __restrict__ qkv){
  int tid = threadIdx.x, wave = tid >> 6, lane = tid & 63;
  int l15 = lane & 15, lhi = lane >> 4;
  int pix0 = blockIdx.x*32;
  f32x4 acc[8][2];
  #pragma unroll
  for (int m=0;m<8;m++){ acc[m][0] = f32x4{0,0,0,0}; acc[m][1] = f32x4{0,0,0,0}; }
  #pragma unroll
  for (int kk=0;kk<2;kk++){
    bf16x8 bfr[2];
    #pragma unroll
    for (int q=0;q<2;q++)
      bfr[q] = *(const bf16x8*)(xcl + (size_t)(pix0 + q*16 + l15)*CC + kk*32 + lhi*8);
    #pragma unroll
    for (int m=0;m<8;m++){
      bf16x8 afr = *(const bf16x8*)(Wsw + ((size_t)(kk*32 + wave*8 + m)*64 + lane)*8);
      acc[m][0] = __builtin_amdgcn_mfma_f32_16x16x32_bf16(afr, bfr[0], acc[m][0], 0,0,0);
      acc[m][1] = __builtin_amdgcn_mfma_f32_16x16x32_bf16(afr, bfr[1], acc[m][1], 0,0,0);
    }
  }
  #pragma unroll
  for (int m=0;m<8;m++){
    int o0 = (wave*8 + m)*16 + lhi*4;
    float b0 = bq[o0], b1 = bq[o0+1], b2 = bq[o0+2], b3 = bq[o0+3];
    #pragma unroll
    for (int q=0;q<2;q++){
      int pix = pix0 + q*16 + l15;
      uint2 pk;
      pk.x = (unsigned int)f2bf(acc[m][q][0]+b0) | ((unsigned int)f2bf(acc[m][q][1]+b1) << 16);
      pk.y = (unsigned int)f2bf(acc[m][q][2]+b2) | ((unsigned int)f2bf(acc[m][q][3]+b3) << 16);
      *(uint2*)(qkv + (size_t)pix*QCH + o0) = pk;
    }
  }
}

// ---------------- att MFMA ----------------
__global__ __launch_bounds__(256) void k_att_mfma(const unsigned short* __restrict__ qkv,
    const float* __restrict__ alphas, const float* __restrict__ att0s,
    const float* __restrict__ sp_emb, const int* __restrict__ sp_pos,
    unsigned short* __restrict__ attT){
  int tid = threadIdx.x, wave = tid >> 6, lane = tid & 63;
  int l15 = lane & 15, lhi = lane >> 4;
  int vt = blockIdx.x, h = blockIdx.y, n = blockIdx.z;
  int uhalf = wave & 1, vsel = wave >> 1;
  int v = (vt*2 + vsel)*16 + l15;
  f32x4 acc[5];
  #pragma unroll
  for (int ui=0;ui<5;ui++) acc[ui] = f32x4{0,0,0,0};
  for (int t=0;t<TT;t++){
    size_t rowb = (size_t)(n*TT + t)*VV;
    bf16x8 bfr = bf16x8{};
    if (v < VV) bfr = *(const bf16x8*)(qkv + (rowb + v)*QCH + 256 + h*DD + lhi*8);
    #pragma unroll
    for (int ui=0;ui<5;ui++){
      int u = (uhalf*5+ui)*16 + l15;
      bf16x8 afr = bf16x8{};
      if (u < VV) afr = *(const bf16x8*)(qkv + (rowb + u)*QCH + h*DD + lhi*8);
      acc[ui] = __builtin_amdgcn_mfma_f32_16x16x32_bf16(afr, bfr, acc[ui], 0,0,0);
    }
  }
  float al = alphas[h];
  #pragma unroll
  for (int ui=0;ui<5;ui++){
    int u0 = (uhalf*5+ui)*16 + lhi*4;
    unsigned short hv[4];
    #pragma unroll
    for (int r=0;r<4;r++){
      int u = u0 + r;
      unsigned short val = 0;
      if (u < VV && v < VV){
        float gv = tanhf(acc[ui][r]*(1.f/640.f))*al
                 + att0s[((size_t)h*VV + u)*VV + v]
                 + sp_emb[sp_pos[u*VV + v]*HH + h];
        val = f2bf(gv);
      }
      hv[r] = val;
    }
    uint2 pk;
    pk.x = (unsigned int)hv[0] | ((unsigned int)hv[1] << 16);
    pk.y = (unsigned int)hv[2] | ((unsigned int)hv[3] << 16);
    *(uint2*)(attT + ((size_t)((n*HH+h)*160) + v)*160 + u0) = pk;
  }
}

// ---------------- yapply MFMA -> padded ycl (v-stride 160, sv=v+2) ----------------
__global__ __launch_bounds__(256) void k_yapply_mfma(const unsigned short* __restrict__ attT,
    const unsigned short* __restrict__ xbf, unsigned short* __restrict__ ycl){
  int tid = threadIdx.x, wave = tid >> 6, lane = tid & 63;
  int l15 = lane & 15, lhi = lane >> 4;
  int h = blockIdx.x, t = blockIdx.y, n = blockIdx.z;
  int vtb = (wave & 1)*5, ctb = (wave >> 1)*2;
  f32x4 acc[5][2];
  #pragma unroll
  for (int vi=0;vi<5;vi++){ acc[vi][0] = f32x4{0,0,0,0}; acc[vi][1] = f32x4{0,0,0,0}; }
  #pragma unroll
  for (int kk=0;kk<5;kk++){
    bf16x8 bfr[2];
    #pragma unroll
    for (int ci=0;ci<2;ci++){
      int c = (ctb+ci)*16 + l15;
      bfr[ci] = *(const bf16x8*)(xbf + ((size_t)(n*CC+c)*TT + t)*160 + kk*32 + lhi*8);
    }
    #pragma unroll
    for (int vi=0;vi<5;vi++){
      int v = (vtb+vi)*16 + l15;
      bf16x8 afr = *(const bf16x8*)(attT + ((size_t)((n*HH+h)*160) + v)*160 + kk*32 + lhi*8);
      #pragma unroll
      for (int ci=0;ci<2;ci++)
        acc[vi][ci] = __builtin_amdgcn_mfma_f32_16x16x32_bf16(afr, bfr[ci], acc[vi][ci], 0,0,0);
    }
  }
  size_t pixb = (size_t)(n*TT + t)*YS;
  if (tid < 128){
    int sv = tid >> 6, cc = tid & 63;
    ycl[(pixb + sv)*QCH + h*CC + cc] = 0;
  }
  #pragma unroll
  for (int vi=0;vi<5;vi++){
    int v0 = (vtb+vi)*16 + lhi*4;
    #pragma unroll
    for (int ci=0;ci<2;ci++){
      int c = (ctb+ci)*16 + l15;
      #pragma unroll
      for (int r=0;r<4;r++){
        int v = v0 + r;
        if (v < VV)
          ycl[(pixb + v + 2)*QCH + h*CC + c] = f2bf(acc[vi][ci][r]);
        else if (v < 158)
          ycl[(pixb + v + 2)*QCH + h*CC + c] = 0;
      }
    }
  }
}

// ---------------- conv_out MFMA: async-LDS weights + fused stats ----------------
// grid (5 vt, 5 tq, 16 n); waves: bit0=mhalf, bit1=vsel, bit2=tsel; block = 32v x 4t
__global__ __launch_bounds__(512) void k_conv_out_mfma(const unsigned short* __restrict__ ycl,
    const unsigned short* __restrict__ Wsw, float* __restrict__ out, float* __restrict__ psum){
  __shared__ unsigned short As[20480];   // 40 KB
  __shared__ float ws_ps[8][64][2];      // 4 KB
  int tid = threadIdx.x, wave = tid >> 6, lane = tid & 63;
  int l15 = lane & 15, lhi = lane >> 4;
  int vt = blockIdx.x, tq = blockIdx.y, n = blockIdx.z;
  int mtb = (wave & 1)*4;
  int vsel = (wave >> 1) & 1;
  int tsel = wave >> 2;
  int t0 = tq*4 + tsel*2;
  int v = vt*32 + vsel*16 + l15;
  int vload = v < 151 ? v : 151;
  f32x4 acc[4][2];
  #pragma unroll
  for (int m=0;m<4;m++){ acc[m][0] = f32x4{0,0,0,0}; acc[m][1] = f32x4{0,0,0,0}; }
  const unsigned short* yb = ycl + ((size_t)(n*TT + t0)*YS + vload)*QCH + lhi*8;

  #define STAGE_OUT(kk_) { \
    _Pragma("unroll") \
    for (int it=0; it<5; it++){ \
      int f = it*8 + wave; \
      const unsigned short* gsrc = Wsw + (size_t)(f>>3)*65536 + (size_t)((kk_)*8 + (f&7))*512 + lane*8; \
      GLD_LDS16(gsrc, &As[f*512 + lane*8]); \
    } }

  for (int kk=0; kk<16; kk++){
    __syncthreads();
    STAGE_OUT(kk);
    bf16x8 bfr[2][5];
    #pragma unroll
    for (int tj=0;tj<2;tj++)
      #pragma unroll
      for (int kv=0;kv<5;kv++)
        bfr[tj][kv] = *(const bf16x8*)(yb + ((size_t)tj*YS + kv)*QCH + kk*32);
    asm volatile("s_waitcnt vmcnt(0)" ::: "memory");
    __syncthreads();
    #pragma unroll
    for (int kv=0; kv<5; kv++){
      bf16x8 afr[4];
      #pragma unroll
      for (int m=0;m<4;m++)
        afr[m] = *(const bf16x8*)(&As[(kv*8 + mtb + m)*512 + lane*8]);
      #pragma unroll
      for (int tj=0;tj<2;tj++)
        #pragma unroll
        for (int m=0;m<4;m++)
          acc[m][tj] = __builtin_amdgcn_mfma_f32_16x16x32_bf16(afr[m], bfr[tj][kv], acc[m][tj], 0,0,0);
    }
  }
  bool vok = v < VV;
  if (vok){
    #pragma unroll
    for (int tj=0;tj<2;tj++){
      size_t pb = ((size_t)(n*TT + t0 + tj)*VV + v)*OO;
      #pragma unroll
      for (int m=0;m<4;m++){
        int o0 = (mtb+m)*16 + lhi*4;
        *(float4*)(out + pb + o0) = make_float4(acc[m][tj][0], acc[m][tj][1], acc[m][tj][2], acc[m][tj][3]);
      }
    }
  }
  #pragma unroll
  for (int m=0;m<4;m++){
    #pragma unroll
    for (int r=0;r<4;r++){
      float a0 = vok ? acc[m][0][r] : 0.f;
      float a1 = vok ? acc[m][1][r] : 0.f;
      float s = a0 + a1;
      float q = a0*a0 + a1*a1;
      #pragma unroll
      for (int off=1; off<16; off<<=1){ s += __shfl_xor(s, off); q += __shfl_xor(q, off); }
      if (l15 == 0){
        ws_ps[wave][m*16 + lhi*4 + r][0] = s;
        ws_ps[wave][m*16 + lhi*4 + r][1] = q;
      }
    }
  }
  __syncthreads();
  if (tid < 128){
    int half = tid >> 6, cw = tid & 63;
    float s = ws_ps[half][cw][0] + ws_ps[half+2][cw][0] + ws_ps[half+4][cw][0] + ws_ps[half+6][cw][0];
    float q = ws_ps[half][cw][1] + ws_ps[half+2][cw][1] + ws_ps[half+4][cw][1] + ws_ps[half+6][cw][1];
    int part = blockIdx.x + 5*blockIdx.y + 25*blockIdx.z;
    psum[(size_t)part*256 + tid] = s;
    psum[(size_t)part*256 + 128 + tid] = q;
  }
}

// ---------------- 1x1 conv MFMA + fused stats (tpad for T-padded input) ----------------
__global__ __launch_bounds__(256) void k_conv1x1_mfma(const unsigned short* __restrict__ in,
    const unsigned short* __restrict__ Wsw, float* __restrict__ out, int KT, int tpad,
    float* __restrict__ psum){
  __shared__ float ws_ps[4][64][2];
  int tid = threadIdx.x, wave = tid >> 6, lane = tid & 63;
  int l15 = lane & 15, lhi = lane >> 4;
  int mtb = (wave & 1)*4;
  int pg = wave >> 1;
  int pixb = blockIdx.x*64 + pg*32;
  int KD = KT*32;
  int ipix[2];
  #pragma unroll
  for (int pj=0;pj<2;pj++){
    int pix = pixb + pj*16 + l15;
    ipix[pj] = tpad ? pix + (2*(pix/3000)+1)*150 : pix;
  }
  f32x4 acc[4][2];
  #pragma unroll
  for (int m=0;m<4;m++){ acc[m][0] = f32x4{0,0,0,0}; acc[m][1] = f32x4{0,0,0,0}; }
  for (int kk=0; kk<KT; kk++){
    bf16x8 bfr[2];
    #pragma unroll
    for (int pj=0;pj<2;pj++)
      bfr[pj] = *(const bf16x8*)(in + (size_t)ipix[pj]*KD + kk*32 + lhi*8);
    #pragma unroll
    for (int m=0;m<4;m++){
      bf16x8 afr = *(const bf16x8*)(Wsw + ((size_t)(kk*8 + mtb + m)*64 + lane)*8);
      acc[m][0] = __builtin_amdgcn_mfma_f32_16x16x32_bf16(afr, bfr[0], acc[m][0], 0,0,0);
      acc[m][1] = __builtin_amdgcn_mfma_f32_16x16x32_bf16(afr, bfr[1], acc[m][1], 0,0,0);
    }
  }
  #pragma unroll
  for (int m=0;m<4;m++){
    int o0 = (mtb+m)*16 + lhi*4;
    #pragma unroll
    for (int pj=0;pj<2;pj++){
      int pix = pixb + pj*16 + l15;
      *(float4*)(out + (size_t)pix*OO + o0) = make_float4(acc[m][pj][0], acc[m][pj][1], acc[m][pj][2], acc[m][pj][3]);
    }
  }
  #pragma unroll
  for (int m=0;m<4;m++){
    #pragma unroll
    for (int r=0;r<4;r++){
      float a0 = acc[m][0][r], a1 = acc[m][1][r];
      float s = a0 + a1;
      float q = a0*a0 + a1*a1;
      #pragma unroll
      for (int off=1; off<16; off<<=1){ s += __shfl_xor(s, off); q += __shfl_xor(q, off); }
      if (l15 == 0){
        ws_ps[wave][m*16 + lhi*4 + r][0] = s;
        ws_ps[wave][m*16 + lhi*4 + r][1] = q;
      }
    }
  }
  __syncthreads();
  if (tid < 128){
    int half = tid >> 6, cw = tid & 63;
    float s = ws_ps[half][cw][0] + ws_ps[half+2][cw][0];
    float q = ws_ps[half][cw][1] + ws_ps[half+2][cw][1];
    psum[(size_t)blockIdx.x*256 + tid] = s;
    psum[(size_t)blockIdx.x*256 + 128 + tid] = q;
  }
}

// ---------------- conv_t MFMA: async-LDS weights + fused stats ----------------
__global__ __launch_bounds__(512) void k_conv_t_mfma(const unsigned short* __restrict__ in,
    const unsigned short* __restrict__ Wsw, float* __restrict__ out, float* __restrict__ psum){
  __shared__ unsigned short As[12288];   // 24 KB
  __shared__ float ws_ps[8][64][2];
  int tid = threadIdx.x, wave = tid >> 6, lane = tid & 63;
  int l15 = lane & 15, lhi = lane >> 4;
  int vt = blockIdx.x, tq = blockIdx.y, n = blockIdx.z;
  int mtb = (wave & 1)*4;
  int vsel = (wave >> 1) & 1;
  int tsel = wave >> 2;
  int t0 = tq*4 + tsel*2;
  int v = vt*32 + vsel*16 + l15;
  int vload = v < 149 ? v : 149;
  bool vok = v < VV;
  const unsigned short* ib = in + ((size_t)(n*22 + t0)*VV + vload)*OO + lhi*8;
  f32x4 acc[4][2];
  #pragma unroll
  for (int m=0;m<4;m++){ acc[m][0] = f32x4{0,0,0,0}; acc[m][1] = f32x4{0,0,0,0}; }

  #define STAGE_T(kk_) { \
    _Pragma("unroll") \
    for (int it=0; it<3; it++){ \
      int f = it*8 + wave; \
      const unsigned short* gsrc = Wsw + (size_t)(f>>3)*16384 + (size_t)((kk_)*8 + (f&7))*512 + lane*8; \
      GLD_LDS16(gsrc, &As[f*512 + lane*8]); \
    } }

  for (int kk=0; kk<4; kk++){
    __syncthreads();
    STAGE_T(kk);
    bf16x8 bfr[4];
    #pragma unroll
    for (int r=0;r<4;r++)
      bfr[r] = *(const bf16x8*)(ib + (size_t)r*VV*OO + kk*32);
    asm volatile("s_waitcnt vmcnt(0)" ::: "memory");
    __syncthreads();
    #pragma unroll
    for (int kt=0; kt<3; kt++){
      bf16x8 afr[4];
      #pragma unroll
      for (int m=0;m<4;m++)
        afr[m] = *(const bf16x8*)(&As[(kt*8 + mtb + m)*512 + lane*8]);
      #pragma unroll
      for (int tj=0;tj<2;tj++)
        #pragma unroll
        for (int m=0;m<4;m++)
          acc[m][tj] = __builtin_amdgcn_mfma_f32_16x16x32_bf16(afr[m], bfr[tj+kt], acc[m][tj], 0,0,0);
    }
  }
  if (vok){
    #pragma unroll
    for (int tj=0;tj<2;tj++){
      size_t pb = ((size_t)(n*TT + t0 + tj)*VV + v)*OO;
      #pragma unroll
      for (int m=0;m<4;m++){
        int o0 = (mtb+m)*16 + lhi*4;
        *(float4*)(out + pb + o0) = make_float4(acc[m][tj][0], acc[m][tj][1], acc[m][tj][2], acc[m][tj][3]);
      }
    }
  }
  #pragma unroll
  for (int m=0;m<4;m++){
    #pragma unroll
    for (int r=0;r<4;r++){
      float a0 = vok ? acc[m][0][r] : 0.f;
      float a1 = vok ? acc[m][1][r] : 0.f;
      float s = a0 + a1;
      float q = a0*a0 + a1*a1;
      #pragma unroll
      for (int off=1; off<16; off<<=1){ s += __shfl_xor(s, off); q += __shfl_xor(q, off); }
      if (l15 == 0){
        ws_ps[wave][m*16 + lhi*4 + r][0] = s;
        ws_ps[wave][m*16 + lhi*4 + r][1] = q;
      }
    }
  }
  __syncthreads();
  if (tid < 128){
    int half = tid >> 6, cw = tid & 63;
    float s = ws_ps[half][cw][0] + ws_ps[half+2][cw][0] + ws_ps[half+4][cw][0] + ws_ps[half+6][cw][0];
    float q = ws_ps[half][cw][1] + ws_ps[half+2][cw][1] + ws_ps[half+4][cw][1] + ws_ps[half+6][cw][1];
    int part = blockIdx.x + 5*blockIdx.y + 25*blockIdx.z;
    psum[(size_t)part*256 + tid] = s;
    psum[(size_t)part*256 + 128 + tid] = q;
  }
}

// ---------------- generic stats stage 2 (dual) ----------------
__global__ __launch_bounds__(64) void k_stats2g(const float* __restrict__ psA, int nA, float* __restrict__ stA,
    const float* __restrict__ psB, int nB, float* __restrict__ stB){
  int ch = blockIdx.x & 127, tid = threadIdx.x;
  const float* ps; float* st; int nb;
  if (blockIdx.x < 128){ ps = psA; st = stA; nb = nA; }
  else { ps = psB; st = stB; nb = nB; }
  float s = 0.f, q = 0.f;
  for (int i=tid; i<nb; i+=64){
    s += ps[(size_t)i*256 + ch];
    q += ps[(size_t)i*256 + 128 + ch];
  }
  #pragma unroll
  for (int off=32; off; off>>=1){ s += __shfl_down(s, off); q += __shfl_down(q, off); }
  if (tid == 0){
    float m = s * (1.f/48000.f);
    float var = q * (1.f/48000.f) - m*m;
    st[ch*2] = m;
    st[ch*2+1] = rsqrtf(var + 1e-5f);
  }
}

// ---------------- xs1 = bf16(lrelu(bn(c) + bn_rs(res))), unpadded ----------------
__global__ __launch_bounds__(256) void k_bn_xs(const float* __restrict__ c,
    const float* __restrict__ st, const float* __restrict__ g, const float* __restrict__ be,
    const float* __restrict__ res, const float* __restrict__ st0,
    const float* __restrict__ g0, const float* __restrict__ be0,
    unsigned short* __restrict__ xs){
  int i = (blockIdx.x*256 + threadIdx.x)*4;
  if (i >= NEL) return;
  int ch = i & 127;
  float4 v = *(const float4*)(c + i);
  float4 r = *(const float4*)(res + i);
  float rs0 = (r.x - st0[ch*2+0]) * st0[ch*2+1] * g0[ch+0] + be0[ch+0];
  float rs1 = (r.y - st0[ch*2+2]) * st0[ch*2+3] * g0[ch+1] + be0[ch+1];
  float rs2 = (r.z - st0[ch*2+4]) * st0[ch*2+5] * g0[ch+2] + be0[ch+2];
  float rs3 = (r.w - st0[ch*2+6]) * st0[ch*2+7] * g0[ch+3] + be0[ch+3];
  float o0 = lrelu((v.x - st[ch*2+0]) * st[ch*2+1] * g[ch+0] + be[ch+0] + rs0);
  float o1 = lrelu((v.y - st[ch*2+2]) * st[ch*2+3] * g[ch+1] + be[ch+1] + rs1);
  float o2 = lrelu((v.z - st[ch*2+4]) * st[ch*2+5] * g[ch+2] + be[ch+2] + rs2);
  float o3 = lrelu((v.w - st[ch*2+6]) * st[ch*2+7] * g[ch+3] + be[ch+3] + rs3);
  uint2 pk;
  pk.x = (unsigned int)f2bf(o0) | ((unsigned int)f2bf(o1) << 16);
  pk.y = (unsigned int)f2bf(o2) | ((unsigned int)f2bf(o3) << 16);
  *(uint2*)(xs + i) = pk;
}

// ---------------- xs2 (T-padded [n][22][150][128]); pad slices zeroed ----------------
#define NQ4 1536000   // NEL/4
__global__ __launch_bounds__(256) void k_bn_xs_pad(const float* __restrict__ c,
    const float* __restrict__ st, const float* __restrict__ g, const float* __restrict__ be,
    const float* __restrict__ res, const float* __restrict__ st0,
    const float* __restrict__ g0, const float* __restrict__ be0,
    unsigned short* __restrict__ xs){
  int gi = blockIdx.x*256 + threadIdx.x;
  if (gi >= NQ4){
    int j = gi - NQ4;
    if (j >= 153600) return;
    int p = j*4;
    int n = p / 38400;
    int rem = p - n*38400;
    int side = rem / 19200;
    int off = rem - side*19200;
    int tq = side ? 21 : 0;
    uint2 z = {0,0};
    *(uint2*)(xs + (size_t)(n*22 + tq)*19200 + off) = z;
    return;
  }
  int i = gi*4;
  int ch = i & 127;
  int n = i / 384000;
  float4 v = *(const float4*)(c + i);
  float4 r = *(const float4*)(res + i);
  float rs0 = (r.x - st0[ch*2+0]) * st0[ch*2+1] * g0[ch+0] + be0[ch+0];
  float rs1 = (r.y - st0[ch*2+2]) * st0[ch*2+3] * g0[ch+1] + be0[ch+1];
  float rs2 = (r.z - st0[ch*2+4]) * st0[ch*2+5] * g0[ch+2] + be0[ch+2];
  float rs3 = (r.w - st0[ch*2+6]) * st0[ch*2+7] * g0[ch+3] + be0[ch+3];
  float o0 = lrelu((v.x - st[ch*2+0]) * st[ch*2+1] * g[ch+0] + be[ch+0] + rs0);
  float o1 = lrelu((v.y - st[ch*2+2]) * st[ch*2+3] * g[ch+1] + be[ch+1] + rs1);
  float o2 = lrelu((v.z - st[ch*2+4]) * st[ch*2+5] * g[ch+2] + be[ch+2] + rs2);
  float o3 = lrelu((v.w - st[ch*2+6]) * st[ch*2+7] * g[ch+3] + be[ch+3] + rs3);
  uint2 pk;
  pk.x = (unsigned int)f2bf(o0) | ((unsigned int)f2bf(o1) << 16);
  pk.y = (unsigned int)f2bf(o2) | ((unsigned int)f2bf(o3) << 16);
  *(uint2*)(xs + (size_t)i + (size_t)(2*n+1)*19200) = pk;
}

// ---------------- final: grid (20,16,2) ----------------
__global__ __launch_bounds__(256) void k_final_cl(const float* __restrict__ c3,
    const float* __restrict__ st3, const float* __restrict__ g3, const float* __restrict__ be3,
    const float* __restrict__ c4, const float* __restrict__ st4, const float* __restrict__ g4,
    const float* __restrict__ be4, float* __restrict__ out){
  __shared__ float tile[64][153];
  int tid = threadIdx.x;
  int t = blockIdx.x, n = blockIdx.y;
  int ch0 = blockIdx.z*64;
  size_t pixb = (size_t)(n*TT + t)*VV;
  for (int idx=tid; idx<VV*64; idx+=256){
    int v = idx >> 6, cc = idx & 63;
    int ch = ch0 + cc;
    float a = (c3[(pixb+v)*OO + ch] - st3[ch*2]) * st3[ch*2+1] * g3[ch] + be3[ch];
    float b = (c4[(pixb+v)*OO + ch] - st4[ch*2]) * st4[ch*2+1] * g4[ch] + be4[ch];
    tile[cc][v] = lrelu(a + b);
  }
  __syncthreads();
  for (int idx=tid; idx<64*VV; idx+=256){
    int cc = idx / VV, v = idx - cc*VV;
    out[((size_t)(n*OO + ch0 + cc)*TT + t)*VV + v] = tile[cc][v];
  }
}

extern "C" void kernel_launch(void* const* d_in, const int* in_sizes, int n_in,
                              void* d_out, int out_size, void* d_ws, size_t ws_size,
                              hipStream_t stream) {
  const float* x        = (const float*)d_in[0];
  const float* W_qkv    = (const float*)d_in[1];
  const float* b_qkv    = (const float*)d_in[2];
  const float* alphas   = (const float*)d_in[3];
  const float* att0s    = (const float*)d_in[4];
  const float* degree_emb = (const float*)d_in[5];
  const float* spatial_emb = (const float*)d_in[6];
  const float* W_out    = (const float*)d_in[7];
  const float* g_out    = (const float*)d_in[9];
  const float* be_out   = (const float*)d_in[10];
  const float* W_ff     = (const float*)d_in[11];
  const float* g_ff     = (const float*)d_in[13];
  const float* be_ff    = (const float*)d_in[14];
  const float* W_t      = (const float*)d_in[15];
  const float* g_t      = (const float*)d_in[17];
  const float* be_t     = (const float*)d_in[18];
  const float* W_rs     = (const float*)d_in[19];
  const float* g_rs     = (const float*)d_in[21];
  const float* be_rs    = (const float*)d_in[22];
  const float* W_rt     = (const float*)d_in[23];
  const float* g_rt     = (const float*)d_in[25];
  const float* be_rt    = (const float*)d_in[26];
  const int* all_degree = (const int*)d_in[27];
  const int* spatial_pos= (const int*)d_in[28];

  char* ws = (char*)d_ws;
  unsigned short* qkvcl = (unsigned short*)(ws + 0);
  unsigned short* ycl   = qkvcl;
  float* c4  = (float*)(ws + 0);
  unsigned short* xcl = (unsigned short*)(ws + 52500000);
  float* c1 = (float*)(ws + 52500000);
  float* c2 = c1, *c3 = c1;
  unsigned short* attT = (unsigned short*)(ws + 77100000);
  float* rsb = (float*)(ws + 77100000);
  unsigned short* xclr = (unsigned short*)(ws + 101700000);
  unsigned short* xs1  = (unsigned short*)(ws + 101700000);
  unsigned short* xbf  = (unsigned short*)(ws + 114000000);
  unsigned short* xs2  = (unsigned short*)(ws + 114000000);
  unsigned short* Wq_sw  = (unsigned short*)(ws + 127600000);
  unsigned short* Wout_sw= (unsigned short*)(ws + 127600000 + 65536);
  unsigned short* Wff_sw = (unsigned short*)(ws + 127600000 + 720896);
  unsigned short* Wrt_sw = (unsigned short*)(ws + 127600000 + 753664);
  unsigned short* Wt_sw  = (unsigned short*)(ws + 127600000 + 786432);
  unsigned short* Wrs_sw = (unsigned short*)(ws + 127600000 + 884736);
  float* stats = (float*)(ws + 128600000);
  float* psumA = (float*)(ws + 128700000);          // 768 KB
  float* psumB = (float*)(ws + 129500000);          // 768 KB
  float* out = (float*)d_out;

  WprepArgs wa;
  int base = 0, sz;
  sz = 32*2*64; wa.j[0] = {W_qkv, Wq_sw, 32, 2, 64, 1, 0, base}; base += sz;
  for (int kv=0; kv<5; kv++){
    sz = 8*16*64; wa.j[1+kv] = {W_out, Wout_sw + kv*65536, 8, 16, 2560, 5, kv, base}; base += sz;
  }
  sz = 8*4*64; wa.j[6] = {W_ff, Wff_sw, 8, 4, 128, 1, 0, base}; base += sz;
  sz = 8*4*64; wa.j[7] = {W_rt, Wrt_sw, 8, 4, 128, 1, 0, base}; base += sz;
  for (int kt=0; kt<3; kt++){
    sz = 8*4*64; wa.j[8+kt] = {W_t, Wt_sw + kt*16384, 8, 4, 384, 3, kt, base}; base += sz;
  }
  sz = 8*2*64; wa.j[11] = {W_rs, Wrs_sw, 8, 2, 64, 1, 0, base}; base += sz;
  int total = base;

  k_wprep_all<<<(total+255)/256, 256, 0, stream>>>(wa, total);
  k_xprep<<<dim3(20,16), 256, 0, stream>>>(x, degree_emb, all_degree, xbf, xcl, xclr);
  k_qkv_mfma<<<1500, 256, 0, stream>>>(xcl, Wq_sw, b_qkv, qkvcl);
  k_att_mfma<<<dim3(5,8,16), 256, 0, stream>>>(qkvcl, alphas, att0s, spatial_emb, spatial_pos, attT);
  k_yapply_mfma<<<dim3(8,20,16), 256, 0, stream>>>(attT, xbf, ycl);

  k_conv1x1_mfma<<<750, 256, 0, stream>>>(xclr, Wrs_sw, rsb, 2, 0, psumA);
  k_conv_out_mfma<<<dim3(5,5,16), 512, 0, stream>>>(ycl, Wout_sw, c1, psumB);
  k_stats2g<<<256, 64, 0, stream>>>(psumA, 750, stats + 0, psumB, 400, stats + 256);
  k_bn_xs<<<6000, 256, 0, stream>>>(c1, stats + 256, g_out, be_out,
                                    rsb, stats + 0, g_rs, be_rs, xs1);

  k_conv1x1_mfma<<<750, 256, 0, stream>>>(xs1, Wff_sw, c2, 4, 0, psumA);
  k_stats2g<<<128, 64, 0, stream>>>(psumA, 750, stats + 512, psumA, 0, stats + 512);
  k_bn_xs_pad<<<6600, 256, 0, stream>>>(c2, stats + 512, g_ff, be_ff,
                                        rsb, stats + 0, g_rs, be_rs, xs2);

  k_conv_t_mfma<<<dim3(5,5,16), 512, 0, stream>>>(xs2, Wt_sw, c3, psumA);
  k_conv1x1_mfma<<<750, 256, 0, stream>>>(xs2, Wrt_sw, c4, 4, 1, psumB);
  k_stats2g<<<256, 64, 0, stream>>>(psumA, 400, stats + 768, psumB, 750, stats + 1024);
  k_final_cl<<<dim3(20,16,2), 256, 0, stream>>>(c3, stats + 768, g_t, be_t,
                                                c4, stats + 1024, g_rt, be_rt, out);
}

// Round 14
// 330.674 us; speedup vs baseline: 1.1408x; 1.0851x over previous
//
#include <hip/hip_runtime.h>

#define NN 16
#define CC 64
#define TT 20
#define VV 150
#define HH 8
#define DD 32
#define OO 128
#define TV 3000
#define QCH 512
#define NPIX 48000
#define NEL 6144000
#define YS 160

using bf16x8 = __attribute__((ext_vector_type(8))) short;
using f32x4  = __attribute__((ext_vector_type(4))) float;

__device__ __forceinline__ unsigned short f2bf(float f){
  union { float f; unsigned int i; } x; x.f = f;
  unsigned int r = x.i + 0x7fffu + ((x.i >> 16) & 1u);
  return (unsigned short)(r >> 16);
}
__device__ __forceinline__ float lrelu(float v){ return v > 0.f ? v : 0.1f*v; }

// ---------------- merged weight pre-swizzle ----------------
struct WprepJob { const float* W; unsigned short* dst; int MT, KT, rs, ks, koff, base; };
struct WprepArgs { WprepJob j[12]; };

__global__ __launch_bounds__(256) void k_wprep_all(WprepArgs a, int total){
  int g = blockIdx.x*256 + threadIdx.x;
  if (g >= total) return;
  int s = 0;
  #pragma unroll
  for (int q=1; q<12; q++) if (g >= a.j[q].base) s = q;
  const WprepJob jb = a.j[s];
  int gg = g - jb.base;
  int lane = gg & 63;
  int f = gg >> 6;
  int mt = f % jb.MT, kk = f / jb.MT;
  int row = mt*16 + (lane & 15);
  int kb = kk*32 + (lane >> 4)*8;
  unsigned int pk[4];
  #pragma unroll
  for (int j=0;j<4;j++){
    unsigned short x0 = f2bf(jb.W[(size_t)row*jb.rs + (size_t)(kb+2*j)*jb.ks + jb.koff]);
    unsigned short x1 = f2bf(jb.W[(size_t)row*jb.rs + (size_t)(kb+2*j+1)*jb.ks + jb.koff]);
    pk[j] = (unsigned int)x0 | ((unsigned int)x1 << 16);
  }
  unsigned int* dst = (unsigned int*)(jb.dst + (size_t)gg*8);
  #pragma unroll
  for (int j=0;j<4;j++) dst[j] = pk[j];
}

// ---------------- x prep ----------------
__global__ __launch_bounds__(256) void k_xprep(const float* __restrict__ x,
    const float* __restrict__ degree_emb, const int* __restrict__ all_degree,
    unsigned short* __restrict__ xbf,
    unsigned short* __restrict__ xcl, unsigned short* __restrict__ xclr){
  __shared__ float xl[64][153];
  int tid = threadIdx.x;
  int t = blockIdx.x, n = blockIdx.y;
  for (int idx=tid; idx<64*160; idx+=256){
    int c = idx/160, v = idx - c*160;
    float xv = 0.f;
    if (v < VV){
      xv = x[((size_t)(n*CC+c)*TT + t)*VV + v];
      xl[c][v] = xv;
    }
    xbf[((size_t)(n*CC+c)*TT + t)*160 + v] = f2bf(xv);
  }
  __syncthreads();
  size_t pixb = (size_t)(n*TT + t)*VV;
  for (int idx=tid; idx<4800; idx+=256){
    int v = idx >> 5, c2 = (idx & 31)*2;
    float a0 = xl[c2][v], a1 = xl[c2+1][v];
    unsigned int raw = (unsigned int)f2bf(a0) | ((unsigned int)f2bf(a1) << 16);
    float freq = __expf(-(float)(c2 >> 1) * 0.2878231366f);
    float arg = (float)v * freq;
    int dgi = all_degree[v % 25];
    float b0 = a0 + sinf(arg) + degree_emb[dgi*CC + c2];
    float b1 = a1 + cosf(arg) + degree_emb[dgi*CC + c2 + 1];
    unsigned int bi = (unsigned int)f2bf(b0) | ((unsigned int)f2bf(b1) << 16);
    *(unsigned int*)(xclr + (pixb + v)*CC + c2) = raw;
    *(unsigned int*)(xcl  + (pixb + v)*CC + c2) = bi;
  }
}

// ---------------- qkv MFMA ----------------
__global__ __launch_bounds__(256) void k_qkv_mfma(const unsigned short* __restrict__ xcl,
    const unsigned short* __restrict__ Wsw, const float* __restrict__ bq,
    unsigned short* __restrict__ qkv){
  int tid = threadIdx.x, wave = tid >> 6, lane = tid & 63;
  int l15 = lane & 15, lhi = lane >> 4;
  int pix0 = blockIdx.x*32;
  f32x4 acc[8][2];
  #pragma unroll
  for (int m=0;m<8;m++){ acc[m][0] = f32x4{0,0,0,0}; acc[m][1] = f32x4{0,0,0,0}; }
  #pragma unroll
  for (int kk=0;kk<2;kk++){
    bf16x8 bfr[2];
    #pragma unroll
    for (int q=0;q<2;q++)
      bfr[q] = *(const bf16x8*)(xcl + (size_t)(pix0 + q*16 + l15)*CC + kk*32 + lhi*8);
    #pragma unroll
    for (int m=0;m<8;m++){
      bf16x8 afr = *(const bf16x8*)(Wsw + ((size_t)(kk*32 + wave*8 + m)*64 + lane)*8);
      acc[m][0] = __builtin_amdgcn_mfma_f32_16x16x32_bf16(afr, bfr[0], acc[m][0], 0,0,0);
      acc[m][1] = __builtin_amdgcn_mfma_f32_16x16x32_bf16(afr, bfr[1], acc[m][1], 0,0,0);
    }
  }
  #pragma unroll
  for (int m=0;m<8;m++){
    int o0 = (wave*8 + m)*16 + lhi*4;
    float b0 = bq[o0], b1 = bq[o0+1], b2 = bq[o0+2], b3 = bq[o0+3];
    #pragma unroll
    for (int q=0;q<2;q++){
      int pix = pix0 + q*16 + l15;
      uint2 pk;
      pk.x = (unsigned int)f2bf(acc[m][q][0]+b0) | ((unsigned int)f2bf(acc[m][q][1]+b1) << 16);
      pk.y = (unsigned int)f2bf(acc[m][q][2]+b2) | ((unsigned int)f2bf(acc[m][q][3]+b3) << 16);
      *(uint2*)(qkv + (size_t)pix*QCH + o0) = pk;
    }
  }
}

// ---------------- att MFMA ----------------
__global__ __launch_bounds__(256) void k_att_mfma(const unsigned short* __restrict__ qkv,
    const float* __restrict__ alphas, const float* __restrict__ att0s,
    const float* __restrict__ sp_emb, const int* __restrict__ sp_pos,
    unsigned short* __restrict__ attT){
  int tid = threadIdx.x, wave = tid >> 6, lane = tid & 63;
  int l15 = lane & 15, lhi = lane >> 4;
  int vt = blockIdx.x, h = blockIdx.y, n = blockIdx.z;
  int uhalf = wave & 1, vsel = wave >> 1;
  int v = (vt*2 + vsel)*16 + l15;
  f32x4 acc[5];
  #pragma unroll
  for (int ui=0;ui<5;ui++) acc[ui] = f32x4{0,0,0,0};
  for (int t=0;t<TT;t++){
    size_t rowb = (size_t)(n*TT + t)*VV;
    bf16x8 bfr = bf16x8{};
    if (v < VV) bfr = *(const bf16x8*)(qkv + (rowb + v)*QCH + 256 + h*DD + lhi*8);
    #pragma unroll
    for (int ui=0;ui<5;ui++){
      int u = (uhalf*5+ui)*16 + l15;
      bf16x8 afr = bf16x8{};
      if (u < VV) afr = *(const bf16x8*)(qkv + (rowb + u)*QCH + h*DD + lhi*8);
      acc[ui] = __builtin_amdgcn_mfma_f32_16x16x32_bf16(afr, bfr, acc[ui], 0,0,0);
    }
  }
  float al = alphas[h];
  #pragma unroll
  for (int ui=0;ui<5;ui++){
    int u0 = (uhalf*5+ui)*16 + lhi*4;
    unsigned short hv[4];
    #pragma unroll
    for (int r=0;r<4;r++){
      int u = u0 + r;
      unsigned short val = 0;
      if (u < VV && v < VV){
        float gv = tanhf(acc[ui][r]*(1.f/640.f))*al
                 + att0s[((size_t)h*VV + u)*VV + v]
                 + sp_emb[sp_pos[u*VV + v]*HH + h];
        val = f2bf(gv);
      }
      hv[r] = val;
    }
    uint2 pk;
    pk.x = (unsigned int)hv[0] | ((unsigned int)hv[1] << 16);
    pk.y = (unsigned int)hv[2] | ((unsigned int)hv[3] << 16);
    *(uint2*)(attT + ((size_t)((n*HH+h)*160) + v)*160 + u0) = pk;
  }
}

// ---------------- yapply MFMA -> padded ycl ----------------
__global__ __launch_bounds__(256) void k_yapply_mfma(const unsigned short* __restrict__ attT,
    const unsigned short* __restrict__ xbf, unsigned short* __restrict__ ycl){
  int tid = threadIdx.x, wave = tid >> 6, lane = tid & 63;
  int l15 = lane & 15, lhi = lane >> 4;
  int h = blockIdx.x, t = blockIdx.y, n = blockIdx.z;
  int vtb = (wave & 1)*5, ctb = (wave >> 1)*2;
  f32x4 acc[5][2];
  #pragma unroll
  for (int vi=0;vi<5;vi++){ acc[vi][0] = f32x4{0,0,0,0}; acc[vi][1] = f32x4{0,0,0,0}; }
  #pragma unroll
  for (int kk=0;kk<5;kk++){
    bf16x8 bfr[2];
    #pragma unroll
    for (int ci=0;ci<2;ci++){
      int c = (ctb+ci)*16 + l15;
      bfr[ci] = *(const bf16x8*)(xbf + ((size_t)(n*CC+c)*TT + t)*160 + kk*32 + lhi*8);
    }
    #pragma unroll
    for (int vi=0;vi<5;vi++){
      int v = (vtb+vi)*16 + l15;
      bf16x8 afr = *(const bf16x8*)(attT + ((size_t)((n*HH+h)*160) + v)*160 + kk*32 + lhi*8);
      #pragma unroll
      for (int ci=0;ci<2;ci++)
        acc[vi][ci] = __builtin_amdgcn_mfma_f32_16x16x32_bf16(afr, bfr[ci], acc[vi][ci], 0,0,0);
    }
  }
  size_t pixb = (size_t)(n*TT + t)*YS;
  if (tid < 128){
    int sv = tid >> 6, cc = tid & 63;
    ycl[(pixb + sv)*QCH + h*CC + cc] = 0;
  }
  #pragma unroll
  for (int vi=0;vi<5;vi++){
    int v0 = (vtb+vi)*16 + lhi*4;
    #pragma unroll
    for (int ci=0;ci<2;ci++){
      int c = (ctb+ci)*16 + l15;
      #pragma unroll
      for (int r=0;r<4;r++){
        int v = v0 + r;
        if (v < VV)
          ycl[(pixb + v + 2)*QCH + h*CC + c] = f2bf(acc[vi][ci][r]);
        else if (v < 158)
          ycl[(pixb + v + 2)*QCH + h*CC + c] = 0;
      }
    }
  }
}

// ================= BIG1: conv_out (blocks 0..399) + conv_rs (blocks 400..774) =================
__global__ __launch_bounds__(512) void k_big1(const unsigned short* __restrict__ ycl,
    const unsigned short* __restrict__ Wout, float* __restrict__ c1, float* __restrict__ psB,
    const unsigned short* __restrict__ xclr, const unsigned short* __restrict__ Wrs,
    float* __restrict__ rsb, float* __restrict__ psA){
  __shared__ unsigned short As[20480];   // 40 KB
  __shared__ float ws_ps[8][64][2];      // 4 KB
  int tid = threadIdx.x, wave = tid >> 6, lane = tid & 63;
  int l15 = lane & 15, lhi = lane >> 4;
  int b = blockIdx.x;
  if (b < 400){
    // -------- conv_out path (R10 structure) --------
    int vt = b % 5, tq = (b/5) % 5, n = b/25;
    int mtb = (wave & 1)*4;
    int vsel = (wave >> 1) & 1;
    int tsel = wave >> 2;
    int t0 = tq*4 + tsel*2;
    int v = vt*32 + vsel*16 + l15;
    int vload = v < 151 ? v : 151;
    f32x4 acc[4][2];
    #pragma unroll
    for (int m=0;m<4;m++){ acc[m][0] = f32x4{0,0,0,0}; acc[m][1] = f32x4{0,0,0,0}; }
    const unsigned short* yb = ycl + ((size_t)(n*TT + t0)*YS + vload)*QCH + lhi*8;
    for (int kk=0; kk<16; kk++){
      __syncthreads();
      #pragma unroll
      for (int it=0; it<5; it++){
        int idx = it*512 + tid;
        int f = idx >> 6, ln = idx & 63;
        int kv = f >> 3, mt = f & 7;
        *(uint4*)(As + f*512 + ln*8) =
          *(const uint4*)(Wout + (size_t)kv*65536 + (size_t)(kk*8+mt)*512 + ln*8);
      }
      __syncthreads();
      #pragma unroll
      for (int kv=0; kv<5; kv++){
        bf16x8 afr[4];
        #pragma unroll
        for (int m=0;m<4;m++)
          afr[m] = *(const bf16x8*)(As + (kv*8 + mtb + m)*512 + lane*8);
        #pragma unroll
        for (int tj=0;tj<2;tj++){
          bf16x8 bfr = *(const bf16x8*)(yb + ((size_t)tj*YS + kv)*QCH + kk*32);
          #pragma unroll
          for (int m=0;m<4;m++)
            acc[m][tj] = __builtin_amdgcn_mfma_f32_16x16x32_bf16(afr[m], bfr, acc[m][tj], 0,0,0);
        }
      }
    }
    bool vok = v < VV;
    if (vok){
      #pragma unroll
      for (int tj=0;tj<2;tj++){
        size_t pb = ((size_t)(n*TT + t0 + tj)*VV + v)*OO;
        #pragma unroll
        for (int m=0;m<4;m++){
          int o0 = (mtb+m)*16 + lhi*4;
          *(float4*)(c1 + pb + o0) = make_float4(acc[m][tj][0], acc[m][tj][1], acc[m][tj][2], acc[m][tj][3]);
        }
      }
    }
    #pragma unroll
    for (int m=0;m<4;m++){
      #pragma unroll
      for (int r=0;r<4;r++){
        float a0 = vok ? acc[m][0][r] : 0.f;
        float a1 = vok ? acc[m][1][r] : 0.f;
        float s = a0 + a1;
        float q = a0*a0 + a1*a1;
        #pragma unroll
        for (int off=1; off<16; off<<=1){ s += __shfl_xor(s, off); q += __shfl_xor(q, off); }
        if (l15 == 0){
          ws_ps[wave][m*16 + lhi*4 + r][0] = s;
          ws_ps[wave][m*16 + lhi*4 + r][1] = q;
        }
      }
    }
    __syncthreads();
    if (tid < 128){
      int half = tid >> 6, cw = tid & 63;
      float s = ws_ps[half][cw][0] + ws_ps[half+2][cw][0] + ws_ps[half+4][cw][0] + ws_ps[half+6][cw][0];
      float q = ws_ps[half][cw][1] + ws_ps[half+2][cw][1] + ws_ps[half+4][cw][1] + ws_ps[half+6][cw][1];
      psB[(size_t)b*256 + tid] = s;
      psB[(size_t)b*256 + 128 + tid] = q;
    }
  } else {
    // -------- conv_rs path: 1x1, K=64, 128 pixels/block --------
    int blk = b - 400;
    int mtb = (wave & 1)*4;
    int pg = wave >> 1;                     // 0..3
    int pixb = blk*128 + pg*32;
    f32x4 acc[4][2];
    #pragma unroll
    for (int m=0;m<4;m++){ acc[m][0] = f32x4{0,0,0,0}; acc[m][1] = f32x4{0,0,0,0}; }
    #pragma unroll
    for (int kk=0; kk<2; kk++){
      bf16x8 bfr[2];
      #pragma unroll
      for (int pj=0;pj<2;pj++)
        bfr[pj] = *(const bf16x8*)(xclr + (size_t)(pixb + pj*16 + l15)*64 + kk*32 + lhi*8);
      #pragma unroll
      for (int m=0;m<4;m++){
        bf16x8 afr = *(const bf16x8*)(Wrs + ((size_t)(kk*8 + mtb + m)*64 + lane)*8);
        acc[m][0] = __builtin_amdgcn_mfma_f32_16x16x32_bf16(afr, bfr[0], acc[m][0], 0,0,0);
        acc[m][1] = __builtin_amdgcn_mfma_f32_16x16x32_bf16(afr, bfr[1], acc[m][1], 0,0,0);
      }
    }
    #pragma unroll
    for (int m=0;m<4;m++){
      int o0 = (mtb+m)*16 + lhi*4;
      #pragma unroll
      for (int pj=0;pj<2;pj++){
        int pix = pixb + pj*16 + l15;
        *(float4*)(rsb + (size_t)pix*OO + o0) = make_float4(acc[m][pj][0], acc[m][pj][1], acc[m][pj][2], acc[m][pj][3]);
      }
    }
    #pragma unroll
    for (int m=0;m<4;m++){
      #pragma unroll
      for (int r=0;r<4;r++){
        float a0 = acc[m][0][r], a1 = acc[m][1][r];
        float s = a0 + a1;
        float q = a0*a0 + a1*a1;
        #pragma unroll
        for (int off=1; off<16; off<<=1){ s += __shfl_xor(s, off); q += __shfl_xor(q, off); }
        if (l15 == 0){
          ws_ps[wave][m*16 + lhi*4 + r][0] = s;
          ws_ps[wave][m*16 + lhi*4 + r][1] = q;
        }
      }
    }
    __syncthreads();
    if (tid < 128){
      int half = tid >> 6, cw = tid & 63;
      float s = ws_ps[half][cw][0] + ws_ps[half+2][cw][0] + ws_ps[half+4][cw][0] + ws_ps[half+6][cw][0];
      float q = ws_ps[half][cw][1] + ws_ps[half+2][cw][1] + ws_ps[half+4][cw][1] + ws_ps[half+6][cw][1];
      psA[(size_t)blk*256 + tid] = s;
      psA[(size_t)blk*256 + 128 + tid] = q;
    }
  }
}

// ================= BIG2: conv_t (blocks 0..399) + conv_rt (blocks 400..774) =================
__global__ __launch_bounds__(512) void k_big2(const unsigned short* __restrict__ xs2,
    const unsigned short* __restrict__ Wt, float* __restrict__ c3, float* __restrict__ psA,
    const unsigned short* __restrict__ Wrt, float* __restrict__ c4, float* __restrict__ psB){
  __shared__ unsigned short As[12288];   // 24 KB
  __shared__ float ws_ps[8][64][2];
  int tid = threadIdx.x, wave = tid >> 6, lane = tid & 63;
  int l15 = lane & 15, lhi = lane >> 4;
  int b = blockIdx.x;
  if (b < 400){
    // -------- conv_t path --------
    int vt = b % 5, tq = (b/5) % 5, n = b/25;
    int mtb = (wave & 1)*4;
    int vsel = (wave >> 1) & 1;
    int tsel = wave >> 2;
    int t0 = tq*4 + tsel*2;
    int v = vt*32 + vsel*16 + l15;
    int vload = v < 149 ? v : 149;
    bool vok = v < VV;
    const unsigned short* ib = xs2 + ((size_t)(n*22 + t0)*VV + vload)*OO + lhi*8;
    f32x4 acc[4][2];
    #pragma unroll
    for (int m=0;m<4;m++){ acc[m][0] = f32x4{0,0,0,0}; acc[m][1] = f32x4{0,0,0,0}; }
    for (int kk=0; kk<4; kk++){
      __syncthreads();
      #pragma unroll
      for (int it=0; it<3; it++){
        int idx = it*512 + tid;
        int f = idx >> 6, ln = idx & 63;
        int kt = f >> 3, mt = f & 7;
        *(uint4*)(As + f*512 + ln*8) =
          *(const uint4*)(Wt + (size_t)kt*16384 + (size_t)(kk*8+mt)*512 + ln*8);
      }
      __syncthreads();
      bf16x8 bfr[4];
      #pragma unroll
      for (int r=0;r<4;r++)
        bfr[r] = *(const bf16x8*)(ib + (size_t)r*VV*OO + kk*32);
      #pragma unroll
      for (int kt=0; kt<3; kt++){
        bf16x8 afr[4];
        #pragma unroll
        for (int m=0;m<4;m++)
          afr[m] = *(const bf16x8*)(As + (kt*8 + mtb + m)*512 + lane*8);
        #pragma unroll
        for (int tj=0;tj<2;tj++)
          #pragma unroll
          for (int m=0;m<4;m++)
            acc[m][tj] = __builtin_amdgcn_mfma_f32_16x16x32_bf16(afr[m], bfr[tj+kt], acc[m][tj], 0,0,0);
      }
    }
    if (vok){
      #pragma unroll
      for (int tj=0;tj<2;tj++){
        size_t pb = ((size_t)(n*TT + t0 + tj)*VV + v)*OO;
        #pragma unroll
        for (int m=0;m<4;m++){
          int o0 = (mtb+m)*16 + lhi*4;
          *(float4*)(c3 + pb + o0) = make_float4(acc[m][tj][0], acc[m][tj][1], acc[m][tj][2], acc[m][tj][3]);
        }
      }
    }
    #pragma unroll
    for (int m=0;m<4;m++){
      #pragma unroll
      for (int r=0;r<4;r++){
        float a0 = vok ? acc[m][0][r] : 0.f;
        float a1 = vok ? acc[m][1][r] : 0.f;
        float s = a0 + a1;
        float q = a0*a0 + a1*a1;
        #pragma unroll
        for (int off=1; off<16; off<<=1){ s += __shfl_xor(s, off); q += __shfl_xor(q, off); }
        if (l15 == 0){
          ws_ps[wave][m*16 + lhi*4 + r][0] = s;
          ws_ps[wave][m*16 + lhi*4 + r][1] = q;
        }
      }
    }
    __syncthreads();
    if (tid < 128){
      int half = tid >> 6, cw = tid & 63;
      float s = ws_ps[half][cw][0] + ws_ps[half+2][cw][0] + ws_ps[half+4][cw][0] + ws_ps[half+6][cw][0];
      float q = ws_ps[half][cw][1] + ws_ps[half+2][cw][1] + ws_ps[half+4][cw][1] + ws_ps[half+6][cw][1];
      psA[(size_t)b*256 + tid] = s;
      psA[(size_t)b*256 + 128 + tid] = q;
    }
  } else {
    // -------- conv_rt path: 1x1, K=128, T-padded input, 128 pixels/block --------
    int blk = b - 400;
    int mtb = (wave & 1)*4;
    int pg = wave >> 1;
    int pixb = blk*128 + pg*32;
    int ipix[2];
    #pragma unroll
    for (int pj=0;pj<2;pj++){
      int pix = pixb + pj*16 + l15;
      ipix[pj] = pix + (2*(pix/3000)+1)*150;
    }
    f32x4 acc[4][2];
    #pragma unroll
    for (int m=0;m<4;m++){ acc[m][0] = f32x4{0,0,0,0}; acc[m][1] = f32x4{0,0,0,0}; }
    #pragma unroll
    for (int kk=0; kk<4; kk++){
      bf16x8 bfr[2];
      #pragma unroll
      for (int pj=0;pj<2;pj++)
        bfr[pj] = *(const bf16x8*)(xs2 + (size_t)ipix[pj]*OO + kk*32 + lhi*8);
      #pragma unroll
      for (int m=0;m<4;m++){
        bf16x8 afr = *(const bf16x8*)(Wrt + ((size_t)(kk*8 + mtb + m)*64 + lane)*8);
        acc[m][0] = __builtin_amdgcn_mfma_f32_16x16x32_bf16(afr, bfr[0], acc[m][0], 0,0,0);
        acc[m][1] = __builtin_amdgcn_mfma_f32_16x16x32_bf16(afr, bfr[1], acc[m][1], 0,0,0);
      }
    }
    #pragma unroll
    for (int m=0;m<4;m++){
      int o0 = (mtb+m)*16 + lhi*4;
      #pragma unroll
      for (int pj=0;pj<2;pj++){
        int pix = pixb + pj*16 + l15;
        *(float4*)(c4 + (size_t)pix*OO + o0) = make_float4(acc[m][pj][0], acc[m][pj][1], acc[m][pj][2], acc[m][pj][3]);
      }
    }
    #pragma unroll
    for (int m=0;m<4;m++){
      #pragma unroll
      for (int r=0;r<4;r++){
        float a0 = acc[m][0][r], a1 = acc[m][1][r];
        float s = a0 + a1;
        float q = a0*a0 + a1*a1;
        #pragma unroll
        for (int off=1; off<16; off<<=1){ s += __shfl_xor(s, off); q += __shfl_xor(q, off); }
        if (l15 == 0){
          ws_ps[wave][m*16 + lhi*4 + r][0] = s;
          ws_ps[wave][m*16 + lhi*4 + r][1] = q;
        }
      }
    }
    __syncthreads();
    if (tid < 128){
      int half = tid >> 6, cw = tid & 63;
      float s = ws_ps[half][cw][0] + ws_ps[half+2][cw][0] + ws_ps[half+4][cw][0] + ws_ps[half+6][cw][0];
      float q = ws_ps[half][cw][1] + ws_ps[half+2][cw][1] + ws_ps[half+4][cw][1] + ws_ps[half+6][cw][1];
      psB[(size_t)blk*256 + tid] = s;
      psB[(size_t)blk*256 + 128 + tid] = q;
    }
  }
}

// ---------------- 1x1 conv MFMA + fused stats (ff) ----------------
__global__ __launch_bounds__(256) void k_conv1x1_mfma(const unsigned short* __restrict__ in,
    const unsigned short* __restrict__ Wsw, float* __restrict__ out, int KT, int tpad,
    float* __restrict__ psum){
  __shared__ float ws_ps[4][64][2];
  int tid = threadIdx.x, wave = tid >> 6, lane = tid & 63;
  int l15 = lane & 15, lhi = lane >> 4;
  int mtb = (wave & 1)*4;
  int pg = wave >> 1;
  int pixb = blockIdx.x*64 + pg*32;
  int KD = KT*32;
  int ipix[2];
  #pragma unroll
  for (int pj=0;pj<2;pj++){
    int pix = pixb + pj*16 + l15;
    ipix[pj] = tpad ? pix + (2*(pix/3000)+1)*150 : pix;
  }
  f32x4 acc[4][2];
  #pragma unroll
  for (int m=0;m<4;m++){ acc[m][0] = f32x4{0,0,0,0}; acc[m][1] = f32x4{0,0,0,0}; }
  for (int kk=0; kk<KT; kk++){
    bf16x8 bfr[2];
    #pragma unroll
    for (int pj=0;pj<2;pj++)
      bfr[pj] = *(const bf16x8*)(in + (size_t)ipix[pj]*KD + kk*32 + lhi*8);
    #pragma unroll
    for (int m=0;m<4;m++){
      bf16x8 afr = *(const bf16x8*)(Wsw + ((size_t)(kk*8 + mtb + m)*64 + lane)*8);
      acc[m][0] = __builtin_amdgcn_mfma_f32_16x16x32_bf16(afr, bfr[0], acc[m][0], 0,0,0);
      acc[m][1] = __builtin_amdgcn_mfma_f32_16x16x32_bf16(afr, bfr[1], acc[m][1], 0,0,0);
    }
  }
  #pragma unroll
  for (int m=0;m<4;m++){
    int o0 = (mtb+m)*16 + lhi*4;
    #pragma unroll
    for (int pj=0;pj<2;pj++){
      int pix = pixb + pj*16 + l15;
      *(float4*)(out + (size_t)pix*OO + o0) = make_float4(acc[m][pj][0], acc[m][pj][1], acc[m][pj][2], acc[m][pj][3]);
    }
  }
  #pragma unroll
  for (int m=0;m<4;m++){
    #pragma unroll
    for (int r=0;r<4;r++){
      float a0 = acc[m][0][r], a1 = acc[m][1][r];
      float s = a0 + a1;
      float q = a0*a0 + a1*a1;
      #pragma unroll
      for (int off=1; off<16; off<<=1){ s += __shfl_xor(s, off); q += __shfl_xor(q, off); }
      if (l15 == 0){
        ws_ps[wave][m*16 + lhi*4 + r][0] = s;
        ws_ps[wave][m*16 + lhi*4 + r][1] = q;
      }
    }
  }
  __syncthreads();
  if (tid < 128){
    int half = tid >> 6, cw = tid & 63;
    float s = ws_ps[half][cw][0] + ws_ps[half+2][cw][0];
    float q = ws_ps[half][cw][1] + ws_ps[half+2][cw][1];
    psum[(size_t)blockIdx.x*256 + tid] = s;
    psum[(size_t)blockIdx.x*256 + 128 + tid] = q;
  }
}

// ---------------- generic stats stage 2 (dual) ----------------
__global__ __launch_bounds__(64) void k_stats2g(const float* __restrict__ psA, int nA, float* __restrict__ stA,
    const float* __restrict__ psB, int nB, float* __restrict__ stB){
  int ch = blockIdx.x & 127, tid = threadIdx.x;
  const float* ps; float* st; int nb;
  if (blockIdx.x < 128){ ps = psA; st = stA; nb = nA; }
  else { ps = psB; st = stB; nb = nB; }
  float s = 0.f, q = 0.f;
  for (int i=tid; i<nb; i+=64){
    s += ps[(size_t)i*256 + ch];
    q += ps[(size_t)i*256 + 128 + ch];
  }
  #pragma unroll
  for (int off=32; off; off>>=1){ s += __shfl_down(s, off); q += __shfl_down(q, off); }
  if (tid == 0){
    float m = s * (1.f/48000.f);
    float var = q * (1.f/48000.f) - m*m;
    st[ch*2] = m;
    st[ch*2+1] = rsqrtf(var + 1e-5f);
  }
}

// ---------------- xs1 = bf16(lrelu(bn(c) + bn_rs(res))), unpadded ----------------
__global__ __launch_bounds__(256) void k_bn_xs(const float* __restrict__ c,
    const float* __restrict__ st, const float* __restrict__ g, const float* __restrict__ be,
    const float* __restrict__ res, const float* __restrict__ st0,
    const float* __restrict__ g0, const float* __restrict__ be0,
    unsigned short* __restrict__ xs){
  int i = (blockIdx.x*256 + threadIdx.x)*4;
  if (i >= NEL) return;
  int ch = i & 127;
  float4 v = *(const float4*)(c + i);
  float4 r = *(const float4*)(res + i);
  float rs0 = (r.x - st0[ch*2+0]) * st0[ch*2+1] * g0[ch+0] + be0[ch+0];
  float rs1 = (r.y - st0[ch*2+2]) * st0[ch*2+3] * g0[ch+1] + be0[ch+1];
  float rs2 = (r.z - st0[ch*2+4]) * st0[ch*2+5] * g0[ch+2] + be0[ch+2];
  float rs3 = (r.w - st0[ch*2+6]) * st0[ch*2+7] * g0[ch+3] + be0[ch+3];
  float o0 = lrelu((v.x - st[ch*2+0]) * st[ch*2+1] * g[ch+0] + be[ch+0] + rs0);
  float o1 = lrelu((v.y - st[ch*2+2]) * st[ch*2+3] * g[ch+1] + be[ch+1] + rs1);
  float o2 = lrelu((v.z - st[ch*2+4]) * st[ch*2+5] * g[ch+2] + be[ch+2] + rs2);
  float o3 = lrelu((v.w - st[ch*2+6]) * st[ch*2+7] * g[ch+3] + be[ch+3] + rs3);
  uint2 pk;
  pk.x = (unsigned int)f2bf(o0) | ((unsigned int)f2bf(o1) << 16);
  pk.y = (unsigned int)f2bf(o2) | ((unsigned int)f2bf(o3) << 16);
  *(uint2*)(xs + i) = pk;
}

// ---------------- xs2 (T-padded [n][22][150][128]); pad slices zeroed ----------------
#define NQ4 1536000
__global__ __launch_bounds__(256) void k_bn_xs_pad(const float* __restrict__ c,
    const float* __restrict__ st, const float* __restrict__ g, const float* __restrict__ be,
    const float* __restrict__ res, const float* __restrict__ st0,
    const float* __restrict__ g0, const float* __restrict__ be0,
    unsigned short* __restrict__ xs){
  int gi = blockIdx.x*256 + threadIdx.x;
  if (gi >= NQ4){
    int j = gi - NQ4;
    if (j >= 153600) return;
    int p = j*4;
    int n = p / 38400;
    int rem = p - n*38400;
    int side = rem / 19200;
    int off = rem - side*19200;
    int tq = side ? 21 : 0;
    uint2 z = {0,0};
    *(uint2*)(xs + (size_t)(n*22 + tq)*19200 + off) = z;
    return;
  }
  int i = gi*4;
  int ch = i & 127;
  int n = i / 384000;
  float4 v = *(const float4*)(c + i);
  float4 r = *(const float4*)(res + i);
  float rs0 = (r.x - st0[ch*2+0]) * st0[ch*2+1] * g0[ch+0] + be0[ch+0];
  float rs1 = (r.y - st0[ch*2+2]) * st0[ch*2+3] * g0[ch+1] + be0[ch+1];
  float rs2 = (r.z - st0[ch*2+4]) * st0[ch*2+5] * g0[ch+2] + be0[ch+2];
  float rs3 = (r.w - st0[ch*2+6]) * st0[ch*2+7] * g0[ch+3] + be0[ch+3];
  float o0 = lrelu((v.x - st[ch*2+0]) * st[ch*2+1] * g[ch+0] + be[ch+0] + rs0);
  float o1 = lrelu((v.y - st[ch*2+2]) * st[ch*2+3] * g[ch+1] + be[ch+1] + rs1);
  float o2 = lrelu((v.z - st[ch*2+4]) * st[ch*2+5] * g[ch+2] + be[ch+2] + rs2);
  float o3 = lrelu((v.w - st[ch*2+6]) * st[ch*2+7] * g[ch+3] + be[ch+3] + rs3);
  uint2 pk;
  pk.x = (unsigned int)f2bf(o0) | ((unsigned int)f2bf(o1) << 16);
  pk.y = (unsigned int)f2bf(o2) | ((unsigned int)f2bf(o3) << 16);
  *(uint2*)(xs + (size_t)i + (size_t)(2*n+1)*19200) = pk;
}

// ---------------- final: grid (20,16,2) ----------------
__global__ __launch_bounds__(256) void k_final_cl(const float* __restrict__ c3,
    const float* __restrict__ st3, const float* __restrict__ g3, const float* __restrict__ be3,
    const float* __restrict__ c4, const float* __restrict__ st4, const float* __restrict__ g4,
    const float* __restrict__ be4, float* __restrict__ out){
  __shared__ float tile[64][153];
  int tid = threadIdx.x;
  int t = blockIdx.x, n = blockIdx.y;
  int ch0 = blockIdx.z*64;
  size_t pixb = (size_t)(n*TT + t)*VV;
  for (int idx=tid; idx<VV*64; idx+=256){
    int v = idx >> 6, cc = idx & 63;
    int ch = ch0 + cc;
    float a = (c3[(pixb+v)*OO + ch] - st3[ch*2]) * st3[ch*2+1] * g3[ch] + be3[ch];
    float b = (c4[(pixb+v)*OO + ch] - st4[ch*2]) * st4[ch*2+1] * g4[ch] + be4[ch];
    tile[cc][v] = lrelu(a + b);
  }
  __syncthreads();
  for (int idx=tid; idx<64*VV; idx+=256){
    int cc = idx / VV, v = idx - cc*VV;
    out[((size_t)(n*OO + ch0 + cc)*TT + t)*VV + v] = tile[cc][v];
  }
}

extern "C" void kernel_launch(void* const* d_in, const int* in_sizes, int n_in,
                              void* d_out, int out_size, void* d_ws, size_t ws_size,
                              hipStream_t stream) {
  const float* x        = (const float*)d_in[0];
  const float* W_qkv    = (const float*)d_in[1];
  const float* b_qkv    = (const float*)d_in[2];
  const float* alphas   = (const float*)d_in[3];
  const float* att0s    = (const float*)d_in[4];
  const float* degree_emb = (const float*)d_in[5];
  const float* spatial_emb = (const float*)d_in[6];
  const float* W_out    = (const float*)d_in[7];
  const float* g_out    = (const float*)d_in[9];
  const float* be_out   = (const float*)d_in[10];
  const float* W_ff     = (const float*)d_in[11];
  const float* g_ff     = (const float*)d_in[13];
  const float* be_ff    = (const float*)d_in[14];
  const float* W_t      = (const float*)d_in[15];
  const float* g_t      = (const float*)d_in[17];
  const float* be_t     = (const float*)d_in[18];
  const float* W_rs     = (const float*)d_in[19];
  const float* g_rs     = (const float*)d_in[21];
  const float* be_rs    = (const float*)d_in[22];
  const float* W_rt     = (const float*)d_in[23];
  const float* g_rt     = (const float*)d_in[25];
  const float* be_rt    = (const float*)d_in[26];
  const int* all_degree = (const int*)d_in[27];
  const int* spatial_pos= (const int*)d_in[28];

  char* ws = (char*)d_ws;
  unsigned short* qkvcl = (unsigned short*)(ws + 0);
  unsigned short* ycl   = qkvcl;
  float* c4  = (float*)(ws + 0);
  unsigned short* xcl = (unsigned short*)(ws + 52500000);
  float* c1 = (float*)(ws + 52500000);
  float* c2 = c1, *c3 = c1;
  unsigned short* attT = (unsigned short*)(ws + 77100000);
  float* rsb = (float*)(ws + 77100000);
  unsigned short* xclr = (unsigned short*)(ws + 101700000);
  unsigned short* xs1  = (unsigned short*)(ws + 101700000);
  unsigned short* xbf  = (unsigned short*)(ws + 114000000);
  unsigned short* xs2  = (unsigned short*)(ws + 114000000);
  unsigned short* Wq_sw  = (unsigned short*)(ws + 127600000);
  unsigned short* Wout_sw= (unsigned short*)(ws + 127600000 + 65536);
  unsigned short* Wff_sw = (unsigned short*)(ws + 127600000 + 720896);
  unsigned short* Wrt_sw = (unsigned short*)(ws + 127600000 + 753664);
  unsigned short* Wt_sw  = (unsigned short*)(ws + 127600000 + 786432);
  unsigned short* Wrs_sw = (unsigned short*)(ws + 127600000 + 884736);
  float* stats = (float*)(ws + 128600000);
  float* psumA = (float*)(ws + 128700000);
  float* psumB = (float*)(ws + 129500000);
  float* out = (float*)d_out;

  WprepArgs wa;
  int base = 0, sz;
  sz = 32*2*64; wa.j[0] = {W_qkv, Wq_sw, 32, 2, 64, 1, 0, base}; base += sz;
  for (int kv=0; kv<5; kv++){
    sz = 8*16*64; wa.j[1+kv] = {W_out, Wout_sw + kv*65536, 8, 16, 2560, 5, kv, base}; base += sz;
  }
  sz = 8*4*64; wa.j[6] = {W_ff, Wff_sw, 8, 4, 128, 1, 0, base}; base += sz;
  sz = 8*4*64; wa.j[7] = {W_rt, Wrt_sw, 8, 4, 128, 1, 0, base}; base += sz;
  for (int kt=0; kt<3; kt++){
    sz = 8*4*64; wa.j[8+kt] = {W_t, Wt_sw + kt*16384, 8, 4, 384, 3, kt, base}; base += sz;
  }
  sz = 8*2*64; wa.j[11] = {W_rs, Wrs_sw, 8, 2, 64, 1, 0, base}; base += sz;
  int total = base;

  k_wprep_all<<<(total+255)/256, 256, 0, stream>>>(wa, total);
  k_xprep<<<dim3(20,16), 256, 0, stream>>>(x, degree_emb, all_degree, xbf, xcl, xclr);
  k_qkv_mfma<<<1500, 256, 0, stream>>>(xcl, Wq_sw, b_qkv, qkvcl);
  k_att_mfma<<<dim3(5,8,16), 256, 0, stream>>>(qkvcl, alphas, att0s, spatial_emb, spatial_pos, attT);
  k_yapply_mfma<<<dim3(8,20,16), 256, 0, stream>>>(attT, xbf, ycl);

  k_big1<<<775, 512, 0, stream>>>(ycl, Wout_sw, c1, psumB, xclr, Wrs_sw, rsb, psumA);
  k_stats2g<<<256, 64, 0, stream>>>(psumA, 375, stats + 0, psumB, 400, stats + 256);
  k_bn_xs<<<6000, 256, 0, stream>>>(c1, stats + 256, g_out, be_out,
                                    rsb, stats + 0, g_rs, be_rs, xs1);

  k_conv1x1_mfma<<<750, 256, 0, stream>>>(xs1, Wff_sw, c2, 4, 0, psumA);
  k_stats2g<<<128, 64, 0, stream>>>(psumA, 750, stats + 512, psumA, 0, stats + 512);
  k_bn_xs_pad<<<6600, 256, 0, stream>>>(c2, stats + 512, g_ff, be_ff,
                                        rsb, stats + 0, g_rs, be_rs, xs2);

  k_big2<<<775, 512, 0, stream>>>(xs2, Wt_sw, c3, psumA, Wrt_sw, c4, psumB);
  k_stats2g<<<256, 64, 0, stream>>>(psumA, 400, stats + 768, psumB, 375, stats + 1024);
  k_final_cl<<<dim3(20,16,2), 256, 0, stream>>>(c3, stats + 768, g_t, be_t,
                                                c4, stats + 1024, g_rt, be_rt, out);
}

// Round 15
// 318.168 us; speedup vs baseline: 1.1856x; 1.0393x over previous
//
#include <hip/hip_runtime.h>

#define NN 16
#define CC 64
#define TT 20
#define VV 150
#define HH 8
#define DD 32
#define OO 128
#define TV 3000
#define QCH 512
#define NPIX 48000
#define NEL 6144000
#define YS 160

using bf16x8 = __attribute__((ext_vector_type(8))) short;
using f32x4  = __attribute__((ext_vector_type(4))) float;

__device__ __forceinline__ unsigned short f2bf(float f){
  union { float f; unsigned int i; } x; x.f = f;
  unsigned int r = x.i + 0x7fffu + ((x.i >> 16) & 1u);
  return (unsigned short)(r >> 16);
}
__device__ __forceinline__ float lrelu(float v){ return v > 0.f ? v : 0.1f*v; }

// ---------------- merged prep: wprep (blocks 0..219) + xprep (blocks 220..539) ----------------
struct WprepJob { const float* W; unsigned short* dst; int MT, KT, rs, ks, koff, base; };
struct WprepArgs { WprepJob j[12]; };

__global__ __launch_bounds__(256) void k_prep_all(WprepArgs a, int total,
    const float* __restrict__ x, const float* __restrict__ degree_emb,
    const int* __restrict__ all_degree, unsigned short* __restrict__ xbf,
    unsigned short* __restrict__ xcl, unsigned short* __restrict__ xclr){
  __shared__ float xl[64][153];
  int b = blockIdx.x;
  int tid = threadIdx.x;
  if (b < 220){
    int g = b*256 + tid;
    if (g >= total) return;
    int s = 0;
    #pragma unroll
    for (int q=1; q<12; q++) if (g >= a.j[q].base) s = q;
    const WprepJob jb = a.j[s];
    int gg = g - jb.base;
    int lane = gg & 63;
    int f = gg >> 6;
    int mt = f % jb.MT, kk = f / jb.MT;
    int row = mt*16 + (lane & 15);
    int kb = kk*32 + (lane >> 4)*8;
    unsigned int pk[4];
    #pragma unroll
    for (int j=0;j<4;j++){
      unsigned short x0 = f2bf(jb.W[(size_t)row*jb.rs + (size_t)(kb+2*j)*jb.ks + jb.koff]);
      unsigned short x1 = f2bf(jb.W[(size_t)row*jb.rs + (size_t)(kb+2*j+1)*jb.ks + jb.koff]);
      pk[j] = (unsigned int)x0 | ((unsigned int)x1 << 16);
    }
    unsigned int* dst = (unsigned int*)(jb.dst + (size_t)gg*8);
    #pragma unroll
    for (int j=0;j<4;j++) dst[j] = pk[j];
    return;
  }
  int b2 = b - 220;
  int t = b2 % 20, n = b2 / 20;
  for (int idx=tid; idx<64*160; idx+=256){
    int c = idx/160, v = idx - c*160;
    float xv = 0.f;
    if (v < VV){
      xv = x[((size_t)(n*CC+c)*TT + t)*VV + v];
      xl[c][v] = xv;
    }
    xbf[((size_t)(n*CC+c)*TT + t)*160 + v] = f2bf(xv);
  }
  __syncthreads();
  size_t pixb = (size_t)(n*TT + t)*VV;
  for (int idx=tid; idx<4800; idx+=256){
    int v = idx >> 5, c2 = (idx & 31)*2;
    float a0 = xl[c2][v], a1 = xl[c2+1][v];
    unsigned int raw = (unsigned int)f2bf(a0) | ((unsigned int)f2bf(a1) << 16);
    float freq = __expf(-(float)(c2 >> 1) * 0.2878231366f);
    float arg = (float)v * freq;
    int dgi = all_degree[v % 25];
    float b0 = a0 + sinf(arg) + degree_emb[dgi*CC + c2];
    float b1 = a1 + cosf(arg) + degree_emb[dgi*CC + c2 + 1];
    unsigned int bi = (unsigned int)f2bf(b0) | ((unsigned int)f2bf(b1) << 16);
    *(unsigned int*)(xclr + (pixb + v)*CC + c2) = raw;
    *(unsigned int*)(xcl  + (pixb + v)*CC + c2) = bi;
  }
}

// ---------------- qkv MFMA ----------------
__global__ __launch_bounds__(256) void k_qkv_mfma(const unsigned short* __restrict__ xcl,
    const unsigned short* __restrict__ Wsw, const float* __restrict__ bq,
    unsigned short* __restrict__ qkv){
  int tid = threadIdx.x, wave = tid >> 6, lane = tid & 63;
  int l15 = lane & 15, lhi = lane >> 4;
  int pix0 = blockIdx.x*32;
  f32x4 acc[8][2];
  #pragma unroll
  for (int m=0;m<8;m++){ acc[m][0] = f32x4{0,0,0,0}; acc[m][1] = f32x4{0,0,0,0}; }
  #pragma unroll
  for (int kk=0;kk<2;kk++){
    bf16x8 bfr[2];
    #pragma unroll
    for (int q=0;q<2;q++)
      bfr[q] = *(const bf16x8*)(xcl + (size_t)(pix0 + q*16 + l15)*CC + kk*32 + lhi*8);
    #pragma unroll
    for (int m=0;m<8;m++){
      bf16x8 afr = *(const bf16x8*)(Wsw + ((size_t)(kk*32 + wave*8 + m)*64 + lane)*8);
      acc[m][0] = __builtin_amdgcn_mfma_f32_16x16x32_bf16(afr, bfr[0], acc[m][0], 0,0,0);
      acc[m][1] = __builtin_amdgcn_mfma_f32_16x16x32_bf16(afr, bfr[1], acc[m][1], 0,0,0);
    }
  }
  #pragma unroll
  for (int m=0;m<8;m++){
    int o0 = (wave*8 + m)*16 + lhi*4;
    float b0 = bq[o0], b1 = bq[o0+1], b2 = bq[o0+2], b3 = bq[o0+3];
    #pragma unroll
    for (int q=0;q<2;q++){
      int pix = pix0 + q*16 + l15;
      uint2 pk;
      pk.x = (unsigned int)f2bf(acc[m][q][0]+b0) | ((unsigned int)f2bf(acc[m][q][1]+b1) << 16);
      pk.y = (unsigned int)f2bf(acc[m][q][2]+b2) | ((unsigned int)f2bf(acc[m][q][3]+b3) << 16);
      *(uint2*)(qkv + (size_t)pix*QCH + o0) = pk;
    }
  }
}

// ---------------- att MFMA ----------------
__global__ __launch_bounds__(256) void k_att_mfma(const unsigned short* __restrict__ qkv,
    const float* __restrict__ alphas, const float* __restrict__ att0s,
    const float* __restrict__ sp_emb, const int* __restrict__ sp_pos,
    unsigned short* __restrict__ attT){
  int tid = threadIdx.x, wave = tid >> 6, lane = tid & 63;
  int l15 = lane & 15, lhi = lane >> 4;
  int vt = blockIdx.x, h = blockIdx.y, n = blockIdx.z;
  int uhalf = wave & 1, vsel = wave >> 1;
  int v = (vt*2 + vsel)*16 + l15;
  f32x4 acc[5];
  #pragma unroll
  for (int ui=0;ui<5;ui++) acc[ui] = f32x4{0,0,0,0};
  for (int t=0;t<TT;t++){
    size_t rowb = (size_t)(n*TT + t)*VV;
    bf16x8 bfr = bf16x8{};
    if (v < VV) bfr = *(const bf16x8*)(qkv + (rowb + v)*QCH + 256 + h*DD + lhi*8);
    #pragma unroll
    for (int ui=0;ui<5;ui++){
      int u = (uhalf*5+ui)*16 + l15;
      bf16x8 afr = bf16x8{};
      if (u < VV) afr = *(const bf16x8*)(qkv + (rowb + u)*QCH + h*DD + lhi*8);
      acc[ui] = __builtin_amdgcn_mfma_f32_16x16x32_bf16(afr, bfr, acc[ui], 0,0,0);
    }
  }
  float al = alphas[h];
  #pragma unroll
  for (int ui=0;ui<5;ui++){
    int u0 = (uhalf*5+ui)*16 + lhi*4;
    unsigned short hv[4];
    #pragma unroll
    for (int r=0;r<4;r++){
      int u = u0 + r;
      unsigned short val = 0;
      if (u < VV && v < VV){
        float gv = tanhf(acc[ui][r]*(1.f/640.f))*al
                 + att0s[((size_t)h*VV + u)*VV + v]
                 + sp_emb[sp_pos[u*VV + v]*HH + h];
        val = f2bf(gv);
      }
      hv[r] = val;
    }
    uint2 pk;
    pk.x = (unsigned int)hv[0] | ((unsigned int)hv[1] << 16);
    pk.y = (unsigned int)hv[2] | ((unsigned int)hv[3] << 16);
    *(uint2*)(attT + ((size_t)((n*HH+h)*160) + v)*160 + u0) = pk;
  }
}

// ---------------- yapply MFMA -> padded ycl ----------------
__global__ __launch_bounds__(256) void k_yapply_mfma(const unsigned short* __restrict__ attT,
    const unsigned short* __restrict__ xbf, unsigned short* __restrict__ ycl){
  int tid = threadIdx.x, wave = tid >> 6, lane = tid & 63;
  int l15 = lane & 15, lhi = lane >> 4;
  int h = blockIdx.x, t = blockIdx.y, n = blockIdx.z;
  int vtb = (wave & 1)*5, ctb = (wave >> 1)*2;
  f32x4 acc[5][2];
  #pragma unroll
  for (int vi=0;vi<5;vi++){ acc[vi][0] = f32x4{0,0,0,0}; acc[vi][1] = f32x4{0,0,0,0}; }
  #pragma unroll
  for (int kk=0;kk<5;kk++){
    bf16x8 bfr[2];
    #pragma unroll
    for (int ci=0;ci<2;ci++){
      int c = (ctb+ci)*16 + l15;
      bfr[ci] = *(const bf16x8*)(xbf + ((size_t)(n*CC+c)*TT + t)*160 + kk*32 + lhi*8);
    }
    #pragma unroll
    for (int vi=0;vi<5;vi++){
      int v = (vtb+vi)*16 + l15;
      bf16x8 afr = *(const bf16x8*)(attT + ((size_t)((n*HH+h)*160) + v)*160 + kk*32 + lhi*8);
      #pragma unroll
      for (int ci=0;ci<2;ci++)
        acc[vi][ci] = __builtin_amdgcn_mfma_f32_16x16x32_bf16(afr, bfr[ci], acc[vi][ci], 0,0,0);
    }
  }
  size_t pixb = (size_t)(n*TT + t)*YS;
  if (tid < 128){
    int sv = tid >> 6, cc = tid & 63;
    ycl[(pixb + sv)*QCH + h*CC + cc] = 0;
  }
  #pragma unroll
  for (int vi=0;vi<5;vi++){
    int v0 = (vtb+vi)*16 + lhi*4;
    #pragma unroll
    for (int ci=0;ci<2;ci++){
      int c = (ctb+ci)*16 + l15;
      #pragma unroll
      for (int r=0;r<4;r++){
        int v = v0 + r;
        if (v < VV)
          ycl[(pixb + v + 2)*QCH + h*CC + c] = f2bf(acc[vi][ci][r]);
        else if (v < 158)
          ycl[(pixb + v + 2)*QCH + h*CC + c] = 0;
      }
    }
  }
}

// ================= BIG1: conv_out (0..399) + conv_rs (400..774) =================
__global__ __launch_bounds__(512) void k_big1(const unsigned short* __restrict__ ycl,
    const unsigned short* __restrict__ Wout, float* __restrict__ c1, float* __restrict__ psB,
    const unsigned short* __restrict__ xclr, const unsigned short* __restrict__ Wrs,
    float* __restrict__ rsb, float* __restrict__ psA){
  __shared__ unsigned short As[20480];
  __shared__ float ws_ps[8][64][2];
  int tid = threadIdx.x, wave = tid >> 6, lane = tid & 63;
  int l15 = lane & 15, lhi = lane >> 4;
  int b = blockIdx.x;
  if (b < 400){
    int vt = b % 5, tq = (b/5) % 5, n = b/25;
    int mtb = (wave & 1)*4;
    int vsel = (wave >> 1) & 1;
    int tsel = wave >> 2;
    int t0 = tq*4 + tsel*2;
    int v = vt*32 + vsel*16 + l15;
    int vload = v < 151 ? v : 151;
    f32x4 acc[4][2];
    #pragma unroll
    for (int m=0;m<4;m++){ acc[m][0] = f32x4{0,0,0,0}; acc[m][1] = f32x4{0,0,0,0}; }
    const unsigned short* yb = ycl + ((size_t)(n*TT + t0)*YS + vload)*QCH + lhi*8;
    for (int kk=0; kk<16; kk++){
      __syncthreads();
      #pragma unroll
      for (int it=0; it<5; it++){
        int idx = it*512 + tid;
        int f = idx >> 6, ln = idx & 63;
        int kv = f >> 3, mt = f & 7;
        *(uint4*)(As + f*512 + ln*8) =
          *(const uint4*)(Wout + (size_t)kv*65536 + (size_t)(kk*8+mt)*512 + ln*8);
      }
      __syncthreads();
      #pragma unroll
      for (int kv=0; kv<5; kv++){
        bf16x8 afr[4];
        #pragma unroll
        for (int m=0;m<4;m++)
          afr[m] = *(const bf16x8*)(As + (kv*8 + mtb + m)*512 + lane*8);
        #pragma unroll
        for (int tj=0;tj<2;tj++){
          bf16x8 bfr = *(const bf16x8*)(yb + ((size_t)tj*YS + kv)*QCH + kk*32);
          #pragma unroll
          for (int m=0;m<4;m++)
            acc[m][tj] = __builtin_amdgcn_mfma_f32_16x16x32_bf16(afr[m], bfr, acc[m][tj], 0,0,0);
        }
      }
    }
    bool vok = v < VV;
    if (vok){
      #pragma unroll
      for (int tj=0;tj<2;tj++){
        size_t pb = ((size_t)(n*TT + t0 + tj)*VV + v)*OO;
        #pragma unroll
        for (int m=0;m<4;m++){
          int o0 = (mtb+m)*16 + lhi*4;
          *(float4*)(c1 + pb + o0) = make_float4(acc[m][tj][0], acc[m][tj][1], acc[m][tj][2], acc[m][tj][3]);
        }
      }
    }
    #pragma unroll
    for (int m=0;m<4;m++){
      #pragma unroll
      for (int r=0;r<4;r++){
        float a0 = vok ? acc[m][0][r] : 0.f;
        float a1 = vok ? acc[m][1][r] : 0.f;
        float s = a0 + a1;
        float q = a0*a0 + a1*a1;
        #pragma unroll
        for (int off=1; off<16; off<<=1){ s += __shfl_xor(s, off); q += __shfl_xor(q, off); }
        if (l15 == 0){
          ws_ps[wave][m*16 + lhi*4 + r][0] = s;
          ws_ps[wave][m*16 + lhi*4 + r][1] = q;
        }
      }
    }
    __syncthreads();
    if (tid < 128){
      int half = tid >> 6, cw = tid & 63;
      float s = ws_ps[half][cw][0] + ws_ps[half+2][cw][0] + ws_ps[half+4][cw][0] + ws_ps[half+6][cw][0];
      float q = ws_ps[half][cw][1] + ws_ps[half+2][cw][1] + ws_ps[half+4][cw][1] + ws_ps[half+6][cw][1];
      psB[(size_t)b*256 + tid] = s;
      psB[(size_t)b*256 + 128 + tid] = q;
    }
  } else {
    int blk = b - 400;
    int mtb = (wave & 1)*4;
    int pg = wave >> 1;
    int pixb = blk*128 + pg*32;
    f32x4 acc[4][2];
    #pragma unroll
    for (int m=0;m<4;m++){ acc[m][0] = f32x4{0,0,0,0}; acc[m][1] = f32x4{0,0,0,0}; }
    #pragma unroll
    for (int kk=0; kk<2; kk++){
      bf16x8 bfr[2];
      #pragma unroll
      for (int pj=0;pj<2;pj++)
        bfr[pj] = *(const bf16x8*)(xclr + (size_t)(pixb + pj*16 + l15)*64 + kk*32 + lhi*8);
      #pragma unroll
      for (int m=0;m<4;m++){
        bf16x8 afr = *(const bf16x8*)(Wrs + ((size_t)(kk*8 + mtb + m)*64 + lane)*8);
        acc[m][0] = __builtin_amdgcn_mfma_f32_16x16x32_bf16(afr, bfr[0], acc[m][0], 0,0,0);
        acc[m][1] = __builtin_amdgcn_mfma_f32_16x16x32_bf16(afr, bfr[1], acc[m][1], 0,0,0);
      }
    }
    #pragma unroll
    for (int m=0;m<4;m++){
      int o0 = (mtb+m)*16 + lhi*4;
      #pragma unroll
      for (int pj=0;pj<2;pj++){
        int pix = pixb + pj*16 + l15;
        *(float4*)(rsb + (size_t)pix*OO + o0) = make_float4(acc[m][pj][0], acc[m][pj][1], acc[m][pj][2], acc[m][pj][3]);
      }
    }
    #pragma unroll
    for (int m=0;m<4;m++){
      #pragma unroll
      for (int r=0;r<4;r++){
        float a0 = acc[m][0][r], a1 = acc[m][1][r];
        float s = a0 + a1;
        float q = a0*a0 + a1*a1;
        #pragma unroll
        for (int off=1; off<16; off<<=1){ s += __shfl_xor(s, off); q += __shfl_xor(q, off); }
        if (l15 == 0){
          ws_ps[wave][m*16 + lhi*4 + r][0] = s;
          ws_ps[wave][m*16 + lhi*4 + r][1] = q;
        }
      }
    }
    __syncthreads();
    if (tid < 128){
      int half = tid >> 6, cw = tid & 63;
      float s = ws_ps[half][cw][0] + ws_ps[half+2][cw][0] + ws_ps[half+4][cw][0] + ws_ps[half+6][cw][0];
      float q = ws_ps[half][cw][1] + ws_ps[half+2][cw][1] + ws_ps[half+4][cw][1] + ws_ps[half+6][cw][1];
      psA[(size_t)blk*256 + tid] = s;
      psA[(size_t)blk*256 + 128 + tid] = q;
    }
  }
}

// ================= BIG2: conv_t (0..399) + conv_rt (400..774) =================
__global__ __launch_bounds__(512) void k_big2(const unsigned short* __restrict__ xs2,
    const unsigned short* __restrict__ Wt, float* __restrict__ c3, float* __restrict__ psA,
    const unsigned short* __restrict__ Wrt, float* __restrict__ c4, float* __restrict__ psB){
  __shared__ unsigned short As[12288];
  __shared__ float ws_ps[8][64][2];
  int tid = threadIdx.x, wave = tid >> 6, lane = tid & 63;
  int l15 = lane & 15, lhi = lane >> 4;
  int b = blockIdx.x;
  if (b < 400){
    int vt = b % 5, tq = (b/5) % 5, n = b/25;
    int mtb = (wave & 1)*4;
    int vsel = (wave >> 1) & 1;
    int tsel = wave >> 2;
    int t0 = tq*4 + tsel*2;
    int v = vt*32 + vsel*16 + l15;
    int vload = v < 149 ? v : 149;
    bool vok = v < VV;
    const unsigned short* ib = xs2 + ((size_t)(n*22 + t0)*VV + vload)*OO + lhi*8;
    f32x4 acc[4][2];
    #pragma unroll
    for (int m=0;m<4;m++){ acc[m][0] = f32x4{0,0,0,0}; acc[m][1] = f32x4{0,0,0,0}; }
    for (int kk=0; kk<4; kk++){
      __syncthreads();
      #pragma unroll
      for (int it=0; it<3; it++){
        int idx = it*512 + tid;
        int f = idx >> 6, ln = idx & 63;
        int kt = f >> 3, mt = f & 7;
        *(uint4*)(As + f*512 + ln*8) =
          *(const uint4*)(Wt + (size_t)kt*16384 + (size_t)(kk*8+mt)*512 + ln*8);
      }
      __syncthreads();
      bf16x8 bfr[4];
      #pragma unroll
      for (int r=0;r<4;r++)
        bfr[r] = *(const bf16x8*)(ib + (size_t)r*VV*OO + kk*32);
      #pragma unroll
      for (int kt=0; kt<3; kt++){
        bf16x8 afr[4];
        #pragma unroll
        for (int m=0;m<4;m++)
          afr[m] = *(const bf16x8*)(As + (kt*8 + mtb + m)*512 + lane*8);
        #pragma unroll
        for (int tj=0;tj<2;tj++)
          #pragma unroll
          for (int m=0;m<4;m++)
            acc[m][tj] = __builtin_amdgcn_mfma_f32_16x16x32_bf16(afr[m], bfr[tj+kt], acc[m][tj], 0,0,0);
      }
    }
    if (vok){
      #pragma unroll
      for (int tj=0;tj<2;tj++){
        size_t pb = ((size_t)(n*TT + t0 + tj)*VV + v)*OO;
        #pragma unroll
        for (int m=0;m<4;m++){
          int o0 = (mtb+m)*16 + lhi*4;
          *(float4*)(c3 + pb + o0) = make_float4(acc[m][tj][0], acc[m][tj][1], acc[m][tj][2], acc[m][tj][3]);
        }
      }
    }
    #pragma unroll
    for (int m=0;m<4;m++){
      #pragma unroll
      for (int r=0;r<4;r++){
        float a0 = vok ? acc[m][0][r] : 0.f;
        float a1 = vok ? acc[m][1][r] : 0.f;
        float s = a0 + a1;
        float q = a0*a0 + a1*a1;
        #pragma unroll
        for (int off=1; off<16; off<<=1){ s += __shfl_xor(s, off); q += __shfl_xor(q, off); }
        if (l15 == 0){
          ws_ps[wave][m*16 + lhi*4 + r][0] = s;
          ws_ps[wave][m*16 + lhi*4 + r][1] = q;
        }
      }
    }
    __syncthreads();
    if (tid < 128){
      int half = tid >> 6, cw = tid & 63;
      float s = ws_ps[half][cw][0] + ws_ps[half+2][cw][0] + ws_ps[half+4][cw][0] + ws_ps[half+6][cw][0];
      float q = ws_ps[half][cw][1] + ws_ps[half+2][cw][1] + ws_ps[half+4][cw][1] + ws_ps[half+6][cw][1];
      psA[(size_t)b*256 + tid] = s;
      psA[(size_t)b*256 + 128 + tid] = q;
    }
  } else {
    int blk = b - 400;
    int mtb = (wave & 1)*4;
    int pg = wave >> 1;
    int pixb = blk*128 + pg*32;
    int ipix[2];
    #pragma unroll
    for (int pj=0;pj<2;pj++){
      int pix = pixb + pj*16 + l15;
      ipix[pj] = pix + (2*(pix/3000)+1)*150;
    }
    f32x4 acc[4][2];
    #pragma unroll
    for (int m=0;m<4;m++){ acc[m][0] = f32x4{0,0,0,0}; acc[m][1] = f32x4{0,0,0,0}; }
    #pragma unroll
    for (int kk=0; kk<4; kk++){
      bf16x8 bfr[2];
      #pragma unroll
      for (int pj=0;pj<2;pj++)
        bfr[pj] = *(const bf16x8*)(xs2 + (size_t)ipix[pj]*OO + kk*32 + lhi*8);
      #pragma unroll
      for (int m=0;m<4;m++){
        bf16x8 afr = *(const bf16x8*)(Wrt + ((size_t)(kk*8 + mtb + m)*64 + lane)*8);
        acc[m][0] = __builtin_amdgcn_mfma_f32_16x16x32_bf16(afr, bfr[0], acc[m][0], 0,0,0);
        acc[m][1] = __builtin_amdgcn_mfma_f32_16x16x32_bf16(afr, bfr[1], acc[m][1], 0,0,0);
      }
    }
    #pragma unroll
    for (int m=0;m<4;m++){
      int o0 = (mtb+m)*16 + lhi*4;
      #pragma unroll
      for (int pj=0;pj<2;pj++){
        int pix = pixb + pj*16 + l15;
        *(float4*)(c4 + (size_t)pix*OO + o0) = make_float4(acc[m][pj][0], acc[m][pj][1], acc[m][pj][2], acc[m][pj][3]);
      }
    }
    #pragma unroll
    for (int m=0;m<4;m++){
      #pragma unroll
      for (int r=0;r<4;r++){
        float a0 = acc[m][0][r], a1 = acc[m][1][r];
        float s = a0 + a1;
        float q = a0*a0 + a1*a1;
        #pragma unroll
        for (int off=1; off<16; off<<=1){ s += __shfl_xor(s, off); q += __shfl_xor(q, off); }
        if (l15 == 0){
          ws_ps[wave][m*16 + lhi*4 + r][0] = s;
          ws_ps[wave][m*16 + lhi*4 + r][1] = q;
        }
      }
    }
    __syncthreads();
    if (tid < 128){
      int half = tid >> 6, cw = tid & 63;
      float s = ws_ps[half][cw][0] + ws_ps[half+2][cw][0] + ws_ps[half+4][cw][0] + ws_ps[half+6][cw][0];
      float q = ws_ps[half][cw][1] + ws_ps[half+2][cw][1] + ws_ps[half+4][cw][1] + ws_ps[half+6][cw][1];
      psB[(size_t)blk*256 + tid] = s;
      psB[(size_t)blk*256 + 128 + tid] = q;
    }
  }
}

// ---------------- fused BN(out)+BN(rs)+lrelu -> LDS -> conv_ff MFMA + stats ----------------
// grid 750 x 256 thr; block owns pixels [b*64, b*64+64)
__global__ __launch_bounds__(256) void k_convff_bn(const float* __restrict__ c1,
    const float* __restrict__ st1, const float* __restrict__ g1, const float* __restrict__ be1,
    const float* __restrict__ rsb, const float* __restrict__ st0,
    const float* __restrict__ g0, const float* __restrict__ be0,
    const unsigned short* __restrict__ Wff, float* __restrict__ c2, float* __restrict__ psum){
  __shared__ unsigned short xsl[64*136];   // padded stride 136
  __shared__ float ws_ps[4][64][2];
  int tid = threadIdx.x, wave = tid >> 6, lane = tid & 63;
  int l15 = lane & 15, lhi = lane >> 4;
  int pixb = blockIdx.x*64;
  // phase 1: BN + lrelu -> bf16 LDS
  #pragma unroll
  for (int it=0; it<8; it++){
    int il = (it*256 + tid)*4;
    int ch = il & 127;
    int pixl = il >> 7;
    size_t i = (size_t)pixb*OO + il;
    float4 v = *(const float4*)(c1 + i);
    float4 r = *(const float4*)(rsb + i);
    float rs0 = (r.x - st0[ch*2+0]) * st0[ch*2+1] * g0[ch+0] + be0[ch+0];
    float rs1 = (r.y - st0[ch*2+2]) * st0[ch*2+3] * g0[ch+1] + be0[ch+1];
    float rs2 = (r.z - st0[ch*2+4]) * st0[ch*2+5] * g0[ch+2] + be0[ch+2];
    float rs3 = (r.w - st0[ch*2+6]) * st0[ch*2+7] * g0[ch+3] + be0[ch+3];
    float o0 = lrelu((v.x - st1[ch*2+0]) * st1[ch*2+1] * g1[ch+0] + be1[ch+0] + rs0);
    float o1 = lrelu((v.y - st1[ch*2+2]) * st1[ch*2+3] * g1[ch+1] + be1[ch+1] + rs1);
    float o2 = lrelu((v.z - st1[ch*2+4]) * st1[ch*2+5] * g1[ch+2] + be1[ch+2] + rs2);
    float o3 = lrelu((v.w - st1[ch*2+6]) * st1[ch*2+7] * g1[ch+3] + be1[ch+3] + rs3);
    uint2 pk;
    pk.x = (unsigned int)f2bf(o0) | ((unsigned int)f2bf(o1) << 16);
    pk.y = (unsigned int)f2bf(o2) | ((unsigned int)f2bf(o3) << 16);
    *(uint2*)(&xsl[pixl*136 + ch]) = pk;
  }
  __syncthreads();
  // phase 2: conv 1x1 K=128 from LDS
  int mtb = (wave & 1)*4;
  int pg = wave >> 1;
  f32x4 acc[4][2];
  #pragma unroll
  for (int m=0;m<4;m++){ acc[m][0] = f32x4{0,0,0,0}; acc[m][1] = f32x4{0,0,0,0}; }
  #pragma unroll
  for (int kk=0; kk<4; kk++){
    bf16x8 bfr[2];
    #pragma unroll
    for (int pj=0;pj<2;pj++){
      int p = pg*32 + pj*16 + l15;
      bfr[pj] = *(const bf16x8*)(&xsl[p*136 + kk*32 + lhi*8]);
    }
    #pragma unroll
    for (int m=0;m<4;m++){
      bf16x8 afr = *(const bf16x8*)(Wff + ((size_t)(kk*8 + mtb + m)*64 + lane)*8);
      acc[m][0] = __builtin_amdgcn_mfma_f32_16x16x32_bf16(afr, bfr[0], acc[m][0], 0,0,0);
      acc[m][1] = __builtin_amdgcn_mfma_f32_16x16x32_bf16(afr, bfr[1], acc[m][1], 0,0,0);
    }
  }
  #pragma unroll
  for (int m=0;m<4;m++){
    int o0 = (mtb+m)*16 + lhi*4;
    #pragma unroll
    for (int pj=0;pj<2;pj++){
      int pix = pixb + pg*32 + pj*16 + l15;
      *(float4*)(c2 + (size_t)pix*OO + o0) = make_float4(acc[m][pj][0], acc[m][pj][1], acc[m][pj][2], acc[m][pj][3]);
    }
  }
  #pragma unroll
  for (int m=0;m<4;m++){
    #pragma unroll
    for (int r=0;r<4;r++){
      float a0 = acc[m][0][r], a1 = acc[m][1][r];
      float s = a0 + a1;
      float q = a0*a0 + a1*a1;
      #pragma unroll
      for (int off=1; off<16; off<<=1){ s += __shfl_xor(s, off); q += __shfl_xor(q, off); }
      if (l15 == 0){
        ws_ps[wave][m*16 + lhi*4 + r][0] = s;
        ws_ps[wave][m*16 + lhi*4 + r][1] = q;
      }
    }
  }
  __syncthreads();
  if (tid < 128){
    int half = tid >> 6, cw = tid & 63;
    float s = ws_ps[half][cw][0] + ws_ps[half+2][cw][0];
    float q = ws_ps[half][cw][1] + ws_ps[half+2][cw][1];
    psum[(size_t)blockIdx.x*256 + tid] = s;
    psum[(size_t)blockIdx.x*256 + 128 + tid] = q;
  }
}

// ---------------- generic stats stage 2 (dual) ----------------
__global__ __launch_bounds__(64) void k_stats2g(const float* __restrict__ psA, int nA, float* __restrict__ stA,
    const float* __restrict__ psB, int nB, float* __restrict__ stB){
  int ch = blockIdx.x & 127, tid = threadIdx.x;
  const float* ps; float* st; int nb;
  if (blockIdx.x < 128){ ps = psA; st = stA; nb = nA; }
  else { ps = psB; st = stB; nb = nB; }
  float s = 0.f, q = 0.f;
  for (int i=tid; i<nb; i+=64){
    s += ps[(size_t)i*256 + ch];
    q += ps[(size_t)i*256 + 128 + ch];
  }
  #pragma unroll
  for (int off=32; off; off>>=1){ s += __shfl_down(s, off); q += __shfl_down(q, off); }
  if (tid == 0){
    float m = s * (1.f/48000.f);
    float var = q * (1.f/48000.f) - m*m;
    st[ch*2] = m;
    st[ch*2+1] = rsqrtf(var + 1e-5f);
  }
}

// ---------------- xs2 (T-padded [n][22][150][128]); pad slices zeroed ----------------
#define NQ4 1536000
__global__ __launch_bounds__(256) void k_bn_xs_pad(const float* __restrict__ c,
    const float* __restrict__ st, const float* __restrict__ g, const float* __restrict__ be,
    const float* __restrict__ res, const float* __restrict__ st0,
    const float* __restrict__ g0, const float* __restrict__ be0,
    unsigned short* __restrict__ xs){
  int gi = blockIdx.x*256 + threadIdx.x;
  if (gi >= NQ4){
    int j = gi - NQ4;
    if (j >= 153600) return;
    int p = j*4;
    int n = p / 38400;
    int rem = p - n*38400;
    int side = rem / 19200;
    int off = rem - side*19200;
    int tq = side ? 21 : 0;
    uint2 z = {0,0};
    *(uint2*)(xs + (size_t)(n*22 + tq)*19200 + off) = z;
    return;
  }
  int i = gi*4;
  int ch = i & 127;
  int n = i / 384000;
  float4 v = *(const float4*)(c + i);
  float4 r = *(const float4*)(res + i);
  float rs0 = (r.x - st0[ch*2+0]) * st0[ch*2+1] * g0[ch+0] + be0[ch+0];
  float rs1 = (r.y - st0[ch*2+2]) * st0[ch*2+3] * g0[ch+1] + be0[ch+1];
  float rs2 = (r.z - st0[ch*2+4]) * st0[ch*2+5] * g0[ch+2] + be0[ch+2];
  float rs3 = (r.w - st0[ch*2+6]) * st0[ch*2+7] * g0[ch+3] + be0[ch+3];
  float o0 = lrelu((v.x - st[ch*2+0]) * st[ch*2+1] * g[ch+0] + be[ch+0] + rs0);
  float o1 = lrelu((v.y - st[ch*2+2]) * st[ch*2+3] * g[ch+1] + be[ch+1] + rs1);
  float o2 = lrelu((v.z - st[ch*2+4]) * st[ch*2+5] * g[ch+2] + be[ch+2] + rs2);
  float o3 = lrelu((v.w - st[ch*2+6]) * st[ch*2+7] * g[ch+3] + be[ch+3] + rs3);
  uint2 pk;
  pk.x = (unsigned int)f2bf(o0) | ((unsigned int)f2bf(o1) << 16);
  pk.y = (unsigned int)f2bf(o2) | ((unsigned int)f2bf(o3) << 16);
  *(uint2*)(xs + (size_t)i + (size_t)(2*n+1)*19200) = pk;
}

// ---------------- final: grid (20,16,2) ----------------
__global__ __launch_bounds__(256) void k_final_cl(const float* __restrict__ c3,
    const float* __restrict__ st3, const float* __restrict__ g3, const float* __restrict__ be3,
    const float* __restrict__ c4, const float* __restrict__ st4, const float* __restrict__ g4,
    const float* __restrict__ be4, float* __restrict__ out){
  __shared__ float tile[64][153];
  int tid = threadIdx.x;
  int t = blockIdx.x, n = blockIdx.y;
  int ch0 = blockIdx.z*64;
  size_t pixb = (size_t)(n*TT + t)*VV;
  for (int idx=tid; idx<VV*64; idx+=256){
    int v = idx >> 6, cc = idx & 63;
    int ch = ch0 + cc;
    float a = (c3[(pixb+v)*OO + ch] - st3[ch*2]) * st3[ch*2+1] * g3[ch] + be3[ch];
    float b = (c4[(pixb+v)*OO + ch] - st4[ch*2]) * st4[ch*2+1] * g4[ch] + be4[ch];
    tile[cc][v] = lrelu(a + b);
  }
  __syncthreads();
  for (int idx=tid; idx<64*VV; idx+=256){
    int cc = idx / VV, v = idx - cc*VV;
    out[((size_t)(n*OO + ch0 + cc)*TT + t)*VV + v] = tile[cc][v];
  }
}

extern "C" void kernel_launch(void* const* d_in, const int* in_sizes, int n_in,
                              void* d_out, int out_size, void* d_ws, size_t ws_size,
                              hipStream_t stream) {
  const float* x        = (const float*)d_in[0];
  const float* W_qkv    = (const float*)d_in[1];
  const float* b_qkv    = (const float*)d_in[2];
  const float* alphas   = (const float*)d_in[3];
  const float* att0s    = (const float*)d_in[4];
  const float* degree_emb = (const float*)d_in[5];
  const float* spatial_emb = (const float*)d_in[6];
  const float* W_out    = (const float*)d_in[7];
  const float* g_out    = (const float*)d_in[9];
  const float* be_out   = (const float*)d_in[10];
  const float* W_ff     = (const float*)d_in[11];
  const float* g_ff     = (const float*)d_in[13];
  const float* be_ff    = (const float*)d_in[14];
  const float* W_t      = (const float*)d_in[15];
  const float* g_t      = (const float*)d_in[17];
  const float* be_t     = (const float*)d_in[18];
  const float* W_rs     = (const float*)d_in[19];
  const float* g_rs     = (const float*)d_in[21];
  const float* be_rs    = (const float*)d_in[22];
  const float* W_rt     = (const float*)d_in[23];
  const float* g_rt     = (const float*)d_in[25];
  const float* be_rt    = (const float*)d_in[26];
  const int* all_degree = (const int*)d_in[27];
  const int* spatial_pos= (const int*)d_in[28];

  char* ws = (char*)d_ws;
  unsigned short* qkvcl = (unsigned short*)(ws + 0);
  unsigned short* ycl   = qkvcl;
  float* c4  = (float*)(ws + 0);
  unsigned short* xcl = (unsigned short*)(ws + 52500000);
  float* c1 = (float*)(ws + 52500000);
  float* c2 = c1, *c3 = c1;
  unsigned short* attT = (unsigned short*)(ws + 77100000);
  float* rsb = (float*)(ws + 77100000);
  unsigned short* xclr = (unsigned short*)(ws + 101700000);
  unsigned short* xbf  = (unsigned short*)(ws + 114000000);
  unsigned short* xs2  = (unsigned short*)(ws + 114000000);
  unsigned short* Wq_sw  = (unsigned short*)(ws + 127600000);
  unsigned short* Wout_sw= (unsigned short*)(ws + 127600000 + 65536);
  unsigned short* Wff_sw = (unsigned short*)(ws + 127600000 + 720896);
  unsigned short* Wrt_sw = (unsigned short*)(ws + 127600000 + 753664);
  unsigned short* Wt_sw  = (unsigned short*)(ws + 127600000 + 786432);
  unsigned short* Wrs_sw = (unsigned short*)(ws + 127600000 + 884736);
  float* stats = (float*)(ws + 128600000);
  float* psumA = (float*)(ws + 128700000);
  float* psumB = (float*)(ws + 129500000);
  float* out = (float*)d_out;

  WprepArgs wa;
  int base = 0, sz;
  sz = 32*2*64; wa.j[0] = {W_qkv, Wq_sw, 32, 2, 64, 1, 0, base}; base += sz;
  for (int kv=0; kv<5; kv++){
    sz = 8*16*64; wa.j[1+kv] = {W_out, Wout_sw + kv*65536, 8, 16, 2560, 5, kv, base}; base += sz;
  }
  sz = 8*4*64; wa.j[6] = {W_ff, Wff_sw, 8, 4, 128, 1, 0, base}; base += sz;
  sz = 8*4*64; wa.j[7] = {W_rt, Wrt_sw, 8, 4, 128, 1, 0, base}; base += sz;
  for (int kt=0; kt<3; kt++){
    sz = 8*4*64; wa.j[8+kt] = {W_t, Wt_sw + kt*16384, 8, 4, 384, 3, kt, base}; base += sz;
  }
  sz = 8*2*64; wa.j[11] = {W_rs, Wrs_sw, 8, 2, 64, 1, 0, base}; base += sz;
  int total = base;  // 56320 -> 220 blocks

  k_prep_all<<<540, 256, 0, stream>>>(wa, total, x, degree_emb, all_degree, xbf, xcl, xclr);
  k_qkv_mfma<<<1500, 256, 0, stream>>>(xcl, Wq_sw, b_qkv, qkvcl);
  k_att_mfma<<<dim3(5,8,16), 256, 0, stream>>>(qkvcl, alphas, att0s, spatial_emb, spatial_pos, attT);
  k_yapply_mfma<<<dim3(8,20,16), 256, 0, stream>>>(attT, xbf, ycl);

  k_big1<<<775, 512, 0, stream>>>(ycl, Wout_sw, c1, psumB, xclr, Wrs_sw, rsb, psumA);
  k_stats2g<<<256, 64, 0, stream>>>(psumA, 375, stats + 0, psumB, 400, stats + 256);
  k_convff_bn<<<750, 256, 0, stream>>>(c1, stats + 256, g_out, be_out,
                                       rsb, stats + 0, g_rs, be_rs,
                                       Wff_sw, c2, psumA);
  k_stats2g<<<128, 64, 0, stream>>>(psumA, 750, stats + 512, psumA, 0, stats + 512);
  k_bn_xs_pad<<<6600, 256, 0, stream>>>(c2, stats + 512, g_ff, be_ff,
                                        rsb, stats + 0, g_rs, be_rs, xs2);

  k_big2<<<775, 512, 0, stream>>>(xs2, Wt_sw, c3, psumA, Wrt_sw, c4, psumB);
  k_stats2g<<<256, 64, 0, stream>>>(psumA, 400, stats + 768, psumB, 375, stats + 1024);
  k_final_cl<<<dim3(20,16,2), 256, 0, stream>>>(c3, stats + 768, g_t, be_t,
                                                c4, stats + 1024, g_rt, be_rt, out);
}